// Round 4
// baseline (944.749 us; speedup 1.0000x reference)
//
#include <hip/hip_runtime.h>
#include <hip/hip_bf16.h>
#include <stdint.h>

using short8 = __attribute__((ext_vector_type(8))) short;
using us4    = __attribute__((ext_vector_type(4))) unsigned short;
using f32x4  = __attribute__((ext_vector_type(4))) float;
using bf16   = __hip_bfloat16;

constexpr int CB=4, CS=512, CF=16, CD=512, CH=8, CL=6, CDFF=2048, CNC=12, CRPH=64, CDH=64;

__device__ inline void gload_lds16(const void* g, void* l) {
    __builtin_amdgcn_global_load_lds((const __attribute__((address_space(1))) void*)g,
                                     (__attribute__((address_space(3))) void*)l, 16, 0, 0);
}
__device__ inline float bfbits2f(unsigned short u) {
    return __uint_as_float(((uint32_t)u) << 16);
}
__device__ inline unsigned short f2bfbits(float f) {
    return __builtin_bit_cast(unsigned short, __float2bfloat16(f));
}

// ---------------------------------------------------------------------------
// MFMA GEMM core (m97 structure): C[BM][BN] += A[BM][K] * W[BN][K]^T
template<int BM, int BN>
__device__ inline void mm_core(const bf16* A, int lda, const bf16* W, int ldw, int K,
                               char* As, char* Bs, f32x4 (&acc)[BM/32][BN/32]) {
    constexpr int MR = BM/32, NR = BN/32;
    constexpr int AC = (BM*64)/4096;
    constexpr int BC = (BN*64)/4096;
    const int tid  = threadIdx.x;
    const int lane = tid & 63;
    const int wv   = tid >> 6;
    const int wr   = wv >> 1, wc = wv & 1;

    for (int k0 = 0; k0 < K; k0 += 32) {
#pragma unroll
        for (int i = 0; i < AC; i++) {
            int c = i*256 + tid;
            const char* g = (const char*)A + ((size_t)(c>>2) * lda + k0) * 2 + (c&3)*16;
            gload_lds16(g, As + (size_t)(c & ~63) * 16);
        }
#pragma unroll
        for (int i = 0; i < BC; i++) {
            int c = i*256 + tid;
            const char* g = (const char*)W + ((size_t)(c>>2) * ldw + k0) * 2 + (c&3)*16;
            gload_lds16(g, Bs + (size_t)(c & ~63) * 16);
        }
        __syncthreads();
        short8 af[MR], bfv[NR];
        int ko = (lane >> 4) * 16;
#pragma unroll
        for (int m = 0; m < MR; m++)
            af[m] = *(const short8*)(As + (wr*(BM/2) + m*16 + (lane&15)) * 64 + ko);
#pragma unroll
        for (int n = 0; n < NR; n++)
            bfv[n] = *(const short8*)(Bs + (wc*(BN/2) + n*16 + (lane&15)) * 64 + ko);
#pragma unroll
        for (int m = 0; m < MR; m++)
#pragma unroll
            for (int n = 0; n < NR; n++)
                acc[m][n] = __builtin_amdgcn_mfma_f32_16x16x32_bf16(af[m], bfv[n], acc[m][n], 0, 0, 0);
        __syncthreads();
    }
}

// EPI: 0 = bf16 out + bias ; 1 = bf16 out + bias + relu
template<int BM, int BN, int EPI>
__global__ __launch_bounds__(256) void k_mm(const bf16* __restrict__ A, int lda,
                                            const bf16* __restrict__ W, int ldw,
                                            const float* __restrict__ bias,
                                            bf16* __restrict__ Cb, int ldc, int K) {
    __shared__ char smem[(BM+BN)*64];
    const int bm = blockIdx.y * BM, bn = blockIdx.x * BN;
    f32x4 acc[BM/32][BN/32] = {};
    mm_core<BM,BN>(A + (size_t)bm * lda, lda, W + (size_t)bn * ldw, ldw, K,
                   smem, smem + BM*64, acc);
    const int lane = threadIdx.x & 63;
    const int wv = threadIdx.x >> 6, wr = wv>>1, wc = wv&1;
#pragma unroll
    for (int m = 0; m < BM/32; m++)
#pragma unroll
        for (int n = 0; n < BN/32; n++)
#pragma unroll
            for (int j = 0; j < 4; j++) {
                int row = bm + wr*(BM/2) + m*16 + (lane>>4)*4 + j;
                int col = bn + wc*(BN/2) + n*16 + (lane&15);
                float v = acc[m][n][j] + bias[col];
                if (EPI == 1) v = fmaxf(v, 0.0f);
                Cb[(size_t)row*ldc + col] = __float2bfloat16(v);
            }
}

// ---------------------------------------------------------------------------
// Fused GEMM + bias + residual + LayerNorm.
// C[2048][512] = A[2048][K] @ W[512][K]^T + bias;  h = LN(h + C)*lns + lnb
// Block: 32 rows x full 512 cols; 4 waves, wave w covers cols [w*128, w*128+128).
template<int K>
__global__ __launch_bounds__(256) void k_mm_ln(const bf16* __restrict__ A,
                                               const bf16* __restrict__ W,
                                               const float* __restrict__ bias,
                                               float* __restrict__ h,
                                               bf16* __restrict__ hb,
                                               const float* __restrict__ lns,
                                               const float* __restrict__ lnb) {
    __shared__ char As[32*64];      // 2 KB  (32 rows x 32k)
    __shared__ char Bs[512*64];     // 32 KB (512 cols x 32k)
    __shared__ float redS[4][32];
    __shared__ float redQ[4][32];

    const int tid = threadIdx.x, l = tid & 63, w = tid >> 6;
    const int g = l >> 4, c = l & 15;
    const int bm = blockIdx.x * 32;

    f32x4 acc[2][8] = {};

    for (int k0 = 0; k0 < K; k0 += 32) {
        if (tid < 128) {
            int r = tid >> 2, u = tid & 3;
            const char* ga = (const char*)(A + (size_t)(bm + r)*K + k0) + u*16;
            gload_lds16(ga, As + (size_t)(tid & ~63) * 16);
        }
#pragma unroll
        for (int i = 0; i < 8; i++) {
            int s = i*256 + tid;
            int r = s >> 2, u = s & 3;
            const char* gb = (const char*)(W + (size_t)r*K + k0) + u*16;
            gload_lds16(gb, Bs + (size_t)(s & ~63) * 16);
        }
        __syncthreads();
        short8 af[2], bfv[8];
        int ko = g * 16;
#pragma unroll
        for (int m = 0; m < 2; m++)
            af[m] = *(const short8*)(As + (m*16 + c) * 64 + ko);
#pragma unroll
        for (int n = 0; n < 8; n++)
            bfv[n] = *(const short8*)(Bs + (w*128 + n*16 + c) * 64 + ko);
#pragma unroll
        for (int m = 0; m < 2; m++)
#pragma unroll
            for (int n = 0; n < 8; n++)
                acc[m][n] = __builtin_amdgcn_mfma_f32_16x16x32_bf16(af[m], bfv[n], acc[m][n], 0, 0, 0);
        __syncthreads();
    }

    // v = acc + bias + resid; per-row sum / sumsq
    float s_[2][4] = {}, q_[2][4] = {};
#pragma unroll
    for (int m = 0; m < 2; m++)
#pragma unroll
        for (int n = 0; n < 8; n++) {
            int col = w*128 + n*16 + c;
            float bcol = bias[col];
#pragma unroll
            for (int j = 0; j < 4; j++) {
                int row = bm + m*16 + g*4 + j;
                float v = acc[m][n][j] + bcol + h[(size_t)row*CD + col];
                acc[m][n][j] = v;
                s_[m][j] += v;
                q_[m][j] += v*v;
            }
        }
#pragma unroll
    for (int m = 0; m < 2; m++)
#pragma unroll
        for (int j = 0; j < 4; j++) {
#pragma unroll
            for (int off = 1; off < 16; off <<= 1) {
                s_[m][j] += __shfl_xor(s_[m][j], off);
                q_[m][j] += __shfl_xor(q_[m][j], off);
            }
        }
    if (c == 0) {
#pragma unroll
        for (int m = 0; m < 2; m++)
#pragma unroll
            for (int j = 0; j < 4; j++) {
                redS[w][m*16 + g*4 + j] = s_[m][j];
                redQ[w][m*16 + g*4 + j] = q_[m][j];
            }
    }
    __syncthreads();

#pragma unroll
    for (int m = 0; m < 2; m++)
#pragma unroll
        for (int j = 0; j < 4; j++) {
            int rl = m*16 + g*4 + j;
            float S = redS[0][rl] + redS[1][rl] + redS[2][rl] + redS[3][rl];
            float Q = redQ[0][rl] + redQ[1][rl] + redQ[2][rl] + redQ[3][rl];
            float mean = S * (1.0f/CD);
            float var  = Q * (1.0f/CD) - mean*mean;
            float rstd = rsqrtf(var + 1e-5f);
            int row = bm + rl;
#pragma unroll
            for (int n = 0; n < 8; n++) {
                int col = w*128 + n*16 + c;
                float o = (acc[m][n][j] - mean) * rstd * lns[col] + lnb[col];
                h[(size_t)row*CD + col]  = o;
                hb[(size_t)row*CD + col] = __float2bfloat16(o);
            }
        }
}

// ---------------------------------------------------------------------------
// Fused attention: per (b,h) and 64-row Q tile: S^T = K@Q^T (+bias, scale),
// online softmax (q lane-local), P -> LDS (XOR-swizzled), O^T = Vt@P^T.
__global__ __launch_bounds__(256) void k_attn_fused(const bf16* __restrict__ qkv,
                                                    const bf16* __restrict__ vt,
                                                    const bf16* __restrict__ bias,
                                                    bf16* __restrict__ att) {
    __shared__ char Ks[16384];
    __shared__ char Vs[16384];
    __shared__ char Ps[16384];

    const int z = blockIdx.y, b = z >> 3, h = z & 7;
    const int qbase = blockIdx.x * 64;
    const int tid = threadIdx.x, l = tid & 63, w = tid >> 6;
    const int g = l >> 4, c = l & 15, swz = l & 7;
    const int q_global = qbase + w*16 + c;

    const bf16* qrow = qkv + ((size_t)(b*CS + q_global))*(3*CD) + h*CDH;
    short8 bq0 = *(const short8*)(qrow + g*8);
    short8 bq1 = *(const short8*)(qrow + 32 + g*8);
    const bf16* brow = bias + ((size_t)z*CS + q_global)*CS;

    float mrun = -1e30f, lsum = 0.0f;
    f32x4 accO[4] = {};
    char* Pb = Ps + w*4096;

    for (int kv0 = 0; kv0 < CS; kv0 += 128) {
#pragma unroll
        for (int i = 0; i < 4; i++) {
            int s = i*256 + tid;
            int r = s >> 3, u = s & 7;
            const bf16* gk = qkv + ((size_t)(b*CS + kv0 + r))*(3*CD) + CD + h*CDH + ((u ^ (r&7)) * 8);
            gload_lds16(gk, Ks + (size_t)(s & ~63)*16);
        }
#pragma unroll
        for (int i = 0; i < 4; i++) {
            int s = i*256 + tid;
            int d = s >> 4, u = s & 15;
            const bf16* gv = vt + ((size_t)(z*CDH + d))*CS + kv0 + ((u ^ (d&7)) * 8);
            gload_lds16(gv, Vs + (size_t)(s & ~63)*16);
        }
        __syncthreads();

        float sv[8][4];
        float tmax = -1e30f;
#pragma unroll
        for (int n = 0; n < 8; n++) {
            int row = n*16 + c;
            short8 af0 = *(const short8*)(Ks + row*128 + ((g    ^ swz) * 16));
            short8 af1 = *(const short8*)(Ks + row*128 + (((4+g) ^ swz) * 16));
            f32x4 a = {};
            a = __builtin_amdgcn_mfma_f32_16x16x32_bf16(af0, bq0, a, 0, 0, 0);
            a = __builtin_amdgcn_mfma_f32_16x16x32_bf16(af1, bq1, a, 0, 0, 0);
            us4 b4 = *(const us4*)(brow + kv0 + n*16 + g*4);
#pragma unroll
            for (int j = 0; j < 4; j++) {
                sv[n][j] = a[j] * 0.125f + bfbits2f(b4[j]);
                tmax = fmaxf(tmax, sv[n][j]);
            }
        }
        tmax = fmaxf(tmax, __shfl_xor(tmax, 16));
        tmax = fmaxf(tmax, __shfl_xor(tmax, 32));
        float mnew = fmaxf(mrun, tmax);
        float corr = __expf(mrun - mnew);
        float tsum = 0.0f;
#pragma unroll
        for (int n = 0; n < 8; n++)
#pragma unroll
            for (int j = 0; j < 4; j++) {
                float e = __expf(sv[n][j] - mnew);
                sv[n][j] = e;
                tsum += e;
            }
        tsum += __shfl_xor(tsum, 16);
        tsum += __shfl_xor(tsum, 32);
        lsum = lsum * corr + tsum;
        mrun = mnew;
#pragma unroll
        for (int n2 = 0; n2 < 4; n2++)
#pragma unroll
            for (int j = 0; j < 4; j++) accO[n2][j] *= corr;

#pragma unroll
        for (int n = 0; n < 8; n++) {
            us4 pk;
#pragma unroll
            for (int j = 0; j < 4; j++) pk[j] = f2bfbits(sv[n][j]);
            *(us4*)(Pb + c*256 + ((n*32 + g*8) ^ (swz << 4))) = pk;
        }

#pragma unroll
        for (int n2 = 0; n2 < 4; n2++) {
            int d = n2*16 + c;
#pragma unroll
            for (int kk = 0; kk < 4; kk++) {
                short8 av = *(const short8*)(Vs + d*256 + (((kk*4 + g) ^ swz) * 16));
                short8 bp = *(const short8*)(Pb + c*256 + (((kk*64 + g*16) ^ (swz << 4))));
                accO[n2] = __builtin_amdgcn_mfma_f32_16x16x32_bf16(av, bp, accO[n2], 0, 0, 0);
            }
        }
        __syncthreads();
    }

    float inv = 1.0f / lsum;
    bf16* orow = att + ((size_t)(b*CS + q_global))*CD + h*CDH;
#pragma unroll
    for (int n2 = 0; n2 < 4; n2++) {
        us4 o;
#pragma unroll
        for (int j = 0; j < 4; j++) o[j] = f2bfbits(accO[n2][j] * inv);
        *(us4*)(orow + n2*16 + g*4) = o;
    }
}

// transpose V slice: vt[(b,h)][d][s] = qkv_v[(b,s)][h][d]
__global__ __launch_bounds__(256) void k_vt(const bf16* __restrict__ qkv, bf16* __restrict__ vt) {
    __shared__ unsigned short tile[64][65];
    const int bh = blockIdx.y, b = bh >> 3, h = bh & 7;
    const int s0 = blockIdx.x * 64;
    const int t = threadIdx.x, r = t >> 2, quad = t & 3;
    const bf16* src = qkv + ((size_t)(b*CS + s0 + r))*(3*CD) + 2*CD + h*CDH + quad*16;
    short8 v0 = *(const short8*)src;
    short8 v1 = *(const short8*)(src + 8);
#pragma unroll
    for (int j = 0; j < 8; j++) {
        tile[r][quad*16 + j]     = (unsigned short)v0[j];
        tile[r][quad*16 + 8 + j] = (unsigned short)v1[j];
    }
    __syncthreads();
    bf16* out = vt + ((size_t)bh*CDH + r)*CS + s0 + quad*16;
    short8 o0, o1;
#pragma unroll
    for (int j = 0; j < 8; j++) {
        o0[j] = (short)tile[quad*16 + j][r];
        o1[j] = (short)tile[quad*16 + 8 + j][r];
    }
    *(short8*)out = o0;
    *(short8*)(out + 8) = o1;
}

// ---------------------------------------------------------------------------
__global__ void k_standardize(const float* __restrict__ x, float* __restrict__ ts,
                              float* __restrict__ fs) {
    int b = blockIdx.x, ch = blockIdx.y, tid = threadIdx.x;
    __shared__ float red[256];
    float v0 = x[(b*CS + tid)*CF + ch];
    float v1 = x[(b*CS + tid + 256)*CF + ch];
    red[tid] = v0 + v1; __syncthreads();
    for (int w = 128; w > 0; w >>= 1) { if (tid < w) red[tid] += red[tid+w]; __syncthreads(); }
    float mean = red[0] * (1.0f/CS); __syncthreads();
    float d0 = v0-mean, d1 = v1-mean;
    red[tid] = d0*d0 + d1*d1; __syncthreads();
    for (int w = 128; w > 0; w >>= 1) { if (tid < w) red[tid] += red[tid+w]; __syncthreads(); }
    float inv = rsqrtf(red[0]*(1.0f/CS) + 1e-6f);
    float* o = ch == 0 ? ts : fs;
    o[b*CS + tid] = d0*inv; o[b*CS + tid + 256] = d1*inv;
}

__global__ __launch_bounds__(256) void k_relpos(const float* __restrict__ ts, const float* __restrict__ fs,
                         const float* __restrict__ w1, const float* __restrict__ b1,
                         const float* __restrict__ w2, const float* __restrict__ b2,
                         bf16* __restrict__ bias) {
    int idx = blockIdx.x * 256 + threadIdx.x;
    int j = idx & (CS-1), i = (idx >> 9) & (CS-1), b = idx >> 18;
    float dt = ts[b*CS + i] - ts[b*CS + j];
    float df = fs[b*CS + i] - fs[b*CS + j];
    float acc[CH];
#pragma unroll
    for (int h = 0; h < CH; h++) acc[h] = b2[h];
    for (int r = 0; r < CRPH; r++) {
        float hd = fmaxf(w1[r*2]*dt + w1[r*2+1]*df + b1[r], 0.0f);
#pragma unroll
        for (int h = 0; h < CH; h++) acc[h] += w2[h*CRPH + r] * hd;
    }
#pragma unroll
    for (int h = 0; h < CH; h++) {
        float v = fminf(fmaxf(acc[h], -5.0f), 5.0f);
        bias[((size_t)(b*CH + h)*CS + i)*CS + j] = __float2bfloat16(v);
    }
}

__global__ __launch_bounds__(256) void k_embed(const float* __restrict__ x, const float* __restrict__ w,
                        const float* __restrict__ bv, float* __restrict__ h, bf16* __restrict__ hb) {
    int idx = blockIdx.x * 256 + threadIdx.x;
    int d = idx & (CD-1), m = idx >> 9;
    const float* xr = x + m*CF;
    const float* wr = w + d*CF;
    float acc = bv[d];
#pragma unroll
    for (int f = 0; f < CF; f++) acc += xr[f]*wr[f];
    h[idx] = acc; hb[idx] = __float2bfloat16(acc);
}

__global__ __launch_bounds__(256) void k_wconv(const float* __restrict__ a0, const float* __restrict__ a1,
                        const float* __restrict__ a2, const float* __restrict__ a3,
                        bf16* __restrict__ dst) {
    size_t i = ((size_t)blockIdx.x * 256 + threadIdx.x) * 8;
    const float* src; size_t off;
    if (i < 786432)       { src = a0; off = i; }
    else if (i < 1048576) { src = a1; off = i - 786432; }
    else if (i < 2097152) { src = a2; off = i - 1048576; }
    else                  { src = a3; off = i - 2097152; }
    short8 o;
#pragma unroll
    for (int j = 0; j < 8; j++) o[j] = __builtin_bit_cast(short, __float2bfloat16(src[off + j]));
    *(short8*)(void*)(dst + i) = o;
}

// pool: rep[b][d] = mean over s of h[b][s][d]; grid (B, D/64), 256 threads
__global__ __launch_bounds__(256) void k_pool(const float* __restrict__ h, float* __restrict__ rep) {
    int b = blockIdx.x, d0 = blockIdx.y * 64;
    int t = threadIdx.x, dl = t & 63, sg = t >> 6;
    float acc = 0.0f;
    for (int s = sg*128; s < sg*128 + 128; s++)
        acc += h[((size_t)(b*CS + s))*CD + d0 + dl];
    __shared__ float red[256];
    red[t] = acc; __syncthreads();
    if (t < 64)
        rep[b*CD + d0 + dl] = (red[t] + red[t+64] + red[t+128] + red[t+192]) * (1.0f/CS);
}

// fc: out[b][c] = rep[b] . fcw[c] + fcb[c]; grid (B, NC), 64 threads
__global__ void k_fc(const float* __restrict__ rep, const float* __restrict__ fcw,
                     const float* __restrict__ fcb, float* __restrict__ out) {
    int b = blockIdx.x, cc = blockIdx.y, l = threadIdx.x;
    float acc = 0.0f;
    for (int d = l; d < CD; d += 64) acc += rep[b*CD + d] * fcw[cc*CD + d];
    for (int o = 32; o > 0; o >>= 1) acc += __shfl_xor(acc, o);
    if (l == 0) out[b*CNC + cc] = acc + fcb[cc];
}

// ---------------------------------------------------------------------------
extern "C" void kernel_launch(void* const* d_in, const int* in_sizes, int n_in,
                              void* d_out, int out_size, void* d_ws, size_t ws_size,
                              hipStream_t stream) {
    const float* x   = (const float*)d_in[0];
    const float* rw1 = (const float*)d_in[1];
    const float* rb1 = (const float*)d_in[2];
    const float* rw2 = (const float*)d_in[3];
    const float* rb2 = (const float*)d_in[4];
    const float* emw = (const float*)d_in[5];
    const float* emb = (const float*)d_in[6];
    const float* aiw = (const float*)d_in[7];
    const float* aib = (const float*)d_in[8];
    const float* aow = (const float*)d_in[9];
    const float* aob = (const float*)d_in[10];
    const float* f1w = (const float*)d_in[11];
    const float* f1b = (const float*)d_in[12];
    const float* f2w = (const float*)d_in[13];
    const float* f2b = (const float*)d_in[14];
    const float* l1s = (const float*)d_in[15];
    const float* l1b = (const float*)d_in[16];
    const float* l2s = (const float*)d_in[17];
    const float* l2b = (const float*)d_in[18];
    const float* fcw = (const float*)d_in[19];
    const float* fcb = (const float*)d_in[20];
    float* out = (float*)d_out;

    char* p = (char*)d_ws;
    auto alloc = [&](size_t bytes) { char* r = p; p += (bytes + 255) & ~(size_t)255; return r; };
    bf16*  biasb = (bf16*)alloc((size_t)CB*CH*CS*CS*2);    // 16.78 MB
    float* h     = (float*)alloc((size_t)CB*CS*CD*4);      // 4.19 MB
    bf16*  hb    = (bf16*)alloc((size_t)CB*CS*CD*2);       // 2.10 MB
    bf16*  qkvb  = (bf16*)alloc((size_t)CB*CS*3*CD*2);     // 6.29 MB
    bf16*  vtb   = (bf16*)alloc((size_t)CB*CH*CDH*CS*2);   // 2.10 MB
    bf16*  attb  = (bf16*)alloc((size_t)CB*CS*CD*2);       // 2.10 MB
    bf16*  ffb   = (bf16*)alloc((size_t)CB*CS*CDFF*2);     // 8.39 MB
    bf16*  wl    = (bf16*)alloc((size_t)3145728*2);        // 6.29 MB
    float* rep   = (float*)alloc((size_t)CB*CD*4);
    float* ts    = (float*)alloc(CB*CS*4);
    float* fs    = (float*)alloc(CB*CS*4);

    const int M = CB*CS;  // 2048

    k_standardize<<<dim3(CB,2), 256, 0, stream>>>(x, ts, fs);
    k_relpos<<<(CB*CS*CS)/256, 256, 0, stream>>>(ts, fs, rw1, rb1, rw2, rb2, biasb);
    k_embed<<<(M*CD)/256, 256, 0, stream>>>(x, emw, emb, h, hb);

    for (int l = 0; l < CL; l++) {
        const bf16* wl_aiw = wl;
        const bf16* wl_aow = wl + 786432;
        const bf16* wl_f1w = wl + 1048576;
        const bf16* wl_f2w = wl + 2097152;
        k_wconv<<<1536, 256, 0, stream>>>(aiw + (size_t)l*786432, aow + (size_t)l*262144,
                                          f1w + (size_t)l*1048576, f2w + (size_t)l*1048576, wl);
        // qkv = h @ aiw^T + aib
        k_mm<128,128,0><<<dim3(12,16), 256, 0, stream>>>(hb, CD, wl_aiw, CD,
                                                         aib + (size_t)l*3*CD, qkvb, 3*CD, CD);
        // V transpose, fused attention
        k_vt<<<dim3(CS/64, CB*CH), 256, 0, stream>>>(qkvb, vtb);
        k_attn_fused<<<dim3(CS/64, CB*CH), 256, 0, stream>>>(qkvb, vtb, biasb, attb);
        // out projection + residual + LN1 (fused)
        k_mm_ln<CD><<<M/32, 256, 0, stream>>>(attb, wl_aow, aob + (size_t)l*CD,
                                              h, hb, l1s + (size_t)l*CD, l1b + (size_t)l*CD);
        // ff1 (relu)
        k_mm<128,128,1><<<dim3(16,16), 256, 0, stream>>>(hb, CD, wl_f1w, CD,
                                                         f1b + (size_t)l*CDFF, ffb, CDFF, CD);
        // ff2 + residual + LN2 (fused)
        k_mm_ln<CDFF><<<M/32, 256, 0, stream>>>(ffb, wl_f2w, f2b + (size_t)l*CD,
                                                h, hb, l2s + (size_t)l*CD, l2b + (size_t)l*CD);
    }

    k_pool<<<dim3(CB, CD/64), 256, 0, stream>>>(h, rep);
    k_fc<<<dim3(CB, CNC), 64, 0, stream>>>(rep, fcw, fcb, out);
}

// Round 5
// 574.248 us; speedup vs baseline: 1.6452x; 1.6452x over previous
//
#include <hip/hip_runtime.h>
#include <hip/hip_bf16.h>
#include <stdint.h>

using short8 = __attribute__((ext_vector_type(8))) short;
using us4    = __attribute__((ext_vector_type(4))) unsigned short;
using f32x4  = __attribute__((ext_vector_type(4))) float;
using bf16   = __hip_bfloat16;

constexpr int CB=4, CS=512, CF=16, CD=512, CH=8, CL=6, CDFF=2048, CNC=12, CRPH=64, CDH=64;

__device__ inline void gload_lds16(const void* g, void* l) {
    __builtin_amdgcn_global_load_lds((const __attribute__((address_space(1))) void*)g,
                                     (__attribute__((address_space(3))) void*)l, 16, 0, 0);
}
__device__ inline float bfbits2f(unsigned short u) {
    return __uint_as_float(((uint32_t)u) << 16);
}
__device__ inline unsigned short f2bfbits(float f) {
    return __builtin_bit_cast(unsigned short, __float2bfloat16(f));
}

// ---------------------------------------------------------------------------
// MFMA GEMM core, BK=64, XOR-swizzled LDS (rows 128 B; slot ^= row&7).
// Staging: linear LDS dest + inverse-swizzled global source (both-sides rule).
template<int BM, int BN>
__device__ inline void mm_core64(const bf16* A, int lda, const bf16* W, int ldw, int K,
                                 char* As, char* Bs, f32x4 (&acc)[BM/32][BN/32]) {
    constexpr int MR = BM/32, NR = BN/32;
    constexpr int AC = BM/32;   // (BM*128 B)/(256 lanes*16 B)
    constexpr int BC = BN/32;
    const int tid  = threadIdx.x;
    const int lane = tid & 63;
    const int wv   = tid >> 6;
    const int wr   = wv >> 1, wc = wv & 1;
    const int g    = lane >> 4, c = lane & 15;

    for (int k0 = 0; k0 < K; k0 += 64) {
#pragma unroll
        for (int i = 0; i < AC; i++) {
            int s = i*256 + tid;
            int r = s >> 3, u = s & 7;
            const char* gp = (const char*)(A + (size_t)r*lda + k0) + ((u ^ (r&7))*16);
            gload_lds16(gp, As + (size_t)(s & ~63)*16);
        }
#pragma unroll
        for (int i = 0; i < BC; i++) {
            int s = i*256 + tid;
            int r = s >> 3, u = s & 7;
            const char* gp = (const char*)(W + (size_t)r*ldw + k0) + ((u ^ (r&7))*16);
            gload_lds16(gp, Bs + (size_t)(s & ~63)*16);
        }
        __syncthreads();
#pragma unroll
        for (int kk = 0; kk < 2; kk++) {
            short8 af[MR], bfv[NR];
#pragma unroll
            for (int m = 0; m < MR; m++) {
                int row = wr*(BM/2) + m*16 + c;
                af[m] = *(const short8*)(As + row*128 + (((kk*4+g) ^ (row&7))*16));
            }
#pragma unroll
            for (int n = 0; n < NR; n++) {
                int row = wc*(BN/2) + n*16 + c;
                bfv[n] = *(const short8*)(Bs + row*128 + (((kk*4+g) ^ (row&7))*16));
            }
#pragma unroll
            for (int m = 0; m < MR; m++)
#pragma unroll
                for (int n = 0; n < NR; n++)
                    acc[m][n] = __builtin_amdgcn_mfma_f32_16x16x32_bf16(af[m], bfv[n], acc[m][n], 0, 0, 0);
        }
        __syncthreads();
    }
}

// EPI: 0 = bf16+bias ; 1 = bf16+bias+relu ; 2 = f32+bias (bias only on kz==0)
template<int BM, int BN, int EPI, int KSPLIT>
__global__ __launch_bounds__(256) void k_mm(const bf16* __restrict__ A, int lda,
                                            const bf16* __restrict__ W, int ldw,
                                            const float* __restrict__ bias,
                                            bf16* __restrict__ Cb, float* __restrict__ Cf,
                                            int ldc, int K) {
    __shared__ char smem[(BM+BN)*128];
    const int bm = blockIdx.y * BM, bn = blockIdx.x * BN;
    const int kz = (KSPLIT > 1) ? blockIdx.z : 0;
    const int Kper = K / KSPLIT;
    f32x4 acc[BM/32][BN/32] = {};
    mm_core64<BM,BN>(A + (size_t)bm*lda + kz*Kper, lda,
                     W + (size_t)bn*ldw + kz*Kper, ldw, Kper,
                     smem, smem + BM*128, acc);
    const int lane = threadIdx.x & 63;
    const int wv = threadIdx.x >> 6, wr = wv>>1, wc = wv&1;
    float* Cfz = Cf + (size_t)kz * 2048 * ldc;
#pragma unroll
    for (int m = 0; m < BM/32; m++)
#pragma unroll
        for (int n = 0; n < BN/32; n++)
#pragma unroll
            for (int j = 0; j < 4; j++) {
                int row = bm + wr*(BM/2) + m*16 + (lane>>4)*4 + j;
                int col = bn + wc*(BN/2) + n*16 + (lane&15);
                float v = acc[m][n][j] + ((kz == 0) ? bias[col] : 0.0f);
                if (EPI == 1) v = fmaxf(v, 0.0f);
                if (EPI == 2) Cfz[(size_t)row*ldc + col] = v;
                else          Cb[(size_t)row*ldc + col] = __float2bfloat16(v);
            }
}

// qkv GEMM: writes Q,K into qkvb; V columns written transposed into vtb.
__global__ __launch_bounds__(256) void k_mm_qkv(const bf16* __restrict__ A,
                                                const bf16* __restrict__ W,
                                                const float* __restrict__ bias,
                                                bf16* __restrict__ qkvb,
                                                bf16* __restrict__ vtb) {
    constexpr int BM = 128, BN = 128;
    __shared__ char smem[(BM+BN)*128];
    const int bm = blockIdx.y * BM, bn = blockIdx.x * BN;
    f32x4 acc[4][4] = {};
    mm_core64<BM,BN>(A + (size_t)bm*CD, CD, W + (size_t)bn*CD, CD, CD,
                     smem, smem + BM*128, acc);
    const int lane = threadIdx.x & 63;
    const int wv = threadIdx.x >> 6, wr = wv>>1, wc = wv&1;
    const int g = lane >> 4, c = lane & 15;
    if (bn < 2*CD) {
#pragma unroll
        for (int m = 0; m < 4; m++)
#pragma unroll
            for (int n = 0; n < 4; n++)
#pragma unroll
                for (int j = 0; j < 4; j++) {
                    int row = bm + wr*64 + m*16 + g*4 + j;
                    int col = bn + wc*64 + n*16 + c;
                    qkvb[(size_t)row*(3*CD) + col] = __float2bfloat16(acc[m][n][j] + bias[col]);
                }
    } else {
#pragma unroll
        for (int m = 0; m < 4; m++)
#pragma unroll
            for (int n = 0; n < 4; n++) {
                int row0 = bm + wr*64 + m*16 + g*4;
                int col  = bn + wc*64 + n*16 + c;
                int z = (row0 >> 9)*8 + ((col - 2*CD) >> 6);
                int d = (col - 2*CD) & 63;
                int s0 = row0 & 511;
                float bcol = bias[col];
                us4 o;
#pragma unroll
                for (int j = 0; j < 4; j++) o[j] = f2bfbits(acc[m][n][j] + bcol);
                *(us4*)(vtb + ((size_t)z*CDH + d)*CS + s0) = o;
            }
    }
}

// ---------------------------------------------------------------------------
// Fused attention (round-3 proven): per (b,h, 64-q tile): S^T = K@Q^T (+bias),
// online softmax (q lane-local), P -> LDS swizzled, O^T = Vt@P^T.
__global__ __launch_bounds__(256) void k_attn_fused(const bf16* __restrict__ qkv,
                                                    const bf16* __restrict__ vt,
                                                    const bf16* __restrict__ bias,
                                                    bf16* __restrict__ att) {
    __shared__ char Ks[16384];
    __shared__ char Vs[16384];
    __shared__ char Ps[16384];

    const int z = blockIdx.y, b = z >> 3, h = z & 7;
    const int qbase = blockIdx.x * 64;
    const int tid = threadIdx.x, l = tid & 63, w = tid >> 6;
    const int g = l >> 4, c = l & 15, swz = l & 7;
    const int q_global = qbase + w*16 + c;

    const bf16* qrow = qkv + ((size_t)(b*CS + q_global))*(3*CD) + h*CDH;
    short8 bq0 = *(const short8*)(qrow + g*8);
    short8 bq1 = *(const short8*)(qrow + 32 + g*8);
    const bf16* brow = bias + ((size_t)z*CS + q_global)*CS;

    float mrun = -1e30f, lsum = 0.0f;
    f32x4 accO[4] = {};
    char* Pb = Ps + w*4096;

    for (int kv0 = 0; kv0 < CS; kv0 += 128) {
#pragma unroll
        for (int i = 0; i < 4; i++) {
            int s = i*256 + tid;
            int r = s >> 3, u = s & 7;
            const bf16* gk = qkv + ((size_t)(b*CS + kv0 + r))*(3*CD) + CD + h*CDH + ((u ^ (r&7)) * 8);
            gload_lds16(gk, Ks + (size_t)(s & ~63)*16);
        }
#pragma unroll
        for (int i = 0; i < 4; i++) {
            int s = i*256 + tid;
            int d = s >> 4, u = s & 15;
            const bf16* gv = vt + ((size_t)(z*CDH + d))*CS + kv0 + ((u ^ (d&7)) * 8);
            gload_lds16(gv, Vs + (size_t)(s & ~63)*16);
        }
        __syncthreads();

        float sv[8][4];
        float tmax = -1e30f;
#pragma unroll
        for (int n = 0; n < 8; n++) {
            int row = n*16 + c;
            short8 af0 = *(const short8*)(Ks + row*128 + ((g    ^ swz) * 16));
            short8 af1 = *(const short8*)(Ks + row*128 + (((4+g) ^ swz) * 16));
            f32x4 a = {};
            a = __builtin_amdgcn_mfma_f32_16x16x32_bf16(af0, bq0, a, 0, 0, 0);
            a = __builtin_amdgcn_mfma_f32_16x16x32_bf16(af1, bq1, a, 0, 0, 0);
            us4 b4 = *(const us4*)(brow + kv0 + n*16 + g*4);
#pragma unroll
            for (int j = 0; j < 4; j++) {
                sv[n][j] = a[j] * 0.125f + bfbits2f(b4[j]);
                tmax = fmaxf(tmax, sv[n][j]);
            }
        }
        tmax = fmaxf(tmax, __shfl_xor(tmax, 16));
        tmax = fmaxf(tmax, __shfl_xor(tmax, 32));
        float mnew = fmaxf(mrun, tmax);
        float corr = __expf(mrun - mnew);
        float tsum = 0.0f;
#pragma unroll
        for (int n = 0; n < 8; n++)
#pragma unroll
            for (int j = 0; j < 4; j++) {
                float e = __expf(sv[n][j] - mnew);
                sv[n][j] = e;
                tsum += e;
            }
        tsum += __shfl_xor(tsum, 16);
        tsum += __shfl_xor(tsum, 32);
        lsum = lsum * corr + tsum;
        mrun = mnew;
#pragma unroll
        for (int n2 = 0; n2 < 4; n2++)
#pragma unroll
            for (int j = 0; j < 4; j++) accO[n2][j] *= corr;

#pragma unroll
        for (int n = 0; n < 8; n++) {
            us4 pk;
#pragma unroll
            for (int j = 0; j < 4; j++) pk[j] = f2bfbits(sv[n][j]);
            *(us4*)(Pb + c*256 + ((n*32 + g*8) ^ (swz << 4))) = pk;
        }

#pragma unroll
        for (int n2 = 0; n2 < 4; n2++) {
            int d = n2*16 + c;
#pragma unroll
            for (int kk = 0; kk < 4; kk++) {
                short8 av = *(const short8*)(Vs + d*256 + (((kk*4 + g) ^ swz) * 16));
                short8 bp = *(const short8*)(Pb + c*256 + (((kk*64 + g*16) ^ (swz << 4))));
                accO[n2] = __builtin_amdgcn_mfma_f32_16x16x32_bf16(av, bp, accO[n2], 0, 0, 0);
            }
        }
        __syncthreads();
    }

    float inv = 1.0f / lsum;
    bf16* orow = att + ((size_t)(b*CS + q_global))*CD + h*CDH;
#pragma unroll
    for (int n2 = 0; n2 < 4; n2++) {
        us4 o;
#pragma unroll
        for (int j = 0; j < 4; j++) o[j] = f2bfbits(accO[n2][j] * inv);
        *(us4*)(orow + n2*16 + g*4) = o;
    }
}

// ---------------------------------------------------------------------------
__global__ void k_standardize(const float* __restrict__ x, float* __restrict__ ts,
                              float* __restrict__ fs) {
    int b = blockIdx.x, ch = blockIdx.y, tid = threadIdx.x;
    __shared__ float red[256];
    float v0 = x[(b*CS + tid)*CF + ch];
    float v1 = x[(b*CS + tid + 256)*CF + ch];
    red[tid] = v0 + v1; __syncthreads();
    for (int w = 128; w > 0; w >>= 1) { if (tid < w) red[tid] += red[tid+w]; __syncthreads(); }
    float mean = red[0] * (1.0f/CS); __syncthreads();
    float d0 = v0-mean, d1 = v1-mean;
    red[tid] = d0*d0 + d1*d1; __syncthreads();
    for (int w = 128; w > 0; w >>= 1) { if (tid < w) red[tid] += red[tid+w]; __syncthreads(); }
    float inv = rsqrtf(red[0]*(1.0f/CS) + 1e-6f);
    float* o = ch == 0 ? ts : fs;
    o[b*CS + tid] = d0*inv; o[b*CS + tid + 256] = d1*inv;
}

__global__ __launch_bounds__(256) void k_relpos(const float* __restrict__ ts, const float* __restrict__ fs,
                         const float* __restrict__ w1, const float* __restrict__ b1,
                         const float* __restrict__ w2, const float* __restrict__ b2,
                         bf16* __restrict__ bias) {
    int idx = blockIdx.x * 256 + threadIdx.x;
    int j = idx & (CS-1), i = (idx >> 9) & (CS-1), b = idx >> 18;
    float dt = ts[b*CS + i] - ts[b*CS + j];
    float df = fs[b*CS + i] - fs[b*CS + j];
    float acc[CH];
#pragma unroll
    for (int h = 0; h < CH; h++) acc[h] = b2[h];
    for (int r = 0; r < CRPH; r++) {
        float hd = fmaxf(w1[r*2]*dt + w1[r*2+1]*df + b1[r], 0.0f);
#pragma unroll
        for (int h = 0; h < CH; h++) acc[h] += w2[h*CRPH + r] * hd;
    }
#pragma unroll
    for (int h = 0; h < CH; h++) {
        float v = fminf(fmaxf(acc[h], -5.0f), 5.0f);
        bias[((size_t)(b*CH + h)*CS + i)*CS + j] = __float2bfloat16(v);
    }
}

__global__ __launch_bounds__(256) void k_embed(const float* __restrict__ x, const float* __restrict__ w,
                        const float* __restrict__ bv, float* __restrict__ h, bf16* __restrict__ hb) {
    int idx = blockIdx.x * 256 + threadIdx.x;
    int d = idx & (CD-1), m = idx >> 9;
    const float* xr = x + m*CF;
    const float* wr = w + d*CF;
    float acc = bv[d];
#pragma unroll
    for (int f = 0; f < CF; f++) acc += xr[f]*wr[f];
    h[idx] = acc; hb[idx] = __float2bfloat16(acc);
}

// residual + LN; NADD extra f32 slabs summed in
template<int NADD>
__global__ __launch_bounds__(256) void k_ln(float* __restrict__ h, const float* __restrict__ a0,
                     const float* __restrict__ a1,
                     const float* __restrict__ s, const float* __restrict__ bv, bf16* __restrict__ hb) {
    int row = blockIdx.x, tid = threadIdx.x;
    __shared__ float red[256];
    size_t i0 = (size_t)row*CD + tid, i1 = i0 + 256;
    float v0 = h[i0] + a0[i0];
    float v1 = h[i1] + a0[i1];
    if (NADD == 2) { v0 += a1[i0]; v1 += a1[i1]; }
    red[tid] = v0 + v1; __syncthreads();
    for (int w = 128; w > 0; w >>= 1) { if (tid < w) red[tid] += red[tid+w]; __syncthreads(); }
    float mean = red[0] * (1.0f/CD); __syncthreads();
    float d0 = v0-mean, d1 = v1-mean;
    red[tid] = d0*d0 + d1*d1; __syncthreads();
    for (int w = 128; w > 0; w >>= 1) { if (tid < w) red[tid] += red[tid+w]; __syncthreads(); }
    float inv = rsqrtf(red[0]*(1.0f/CD) + 1e-5f);
    float o0 = d0*inv*s[tid] + bv[tid];
    float o1 = d1*inv*s[tid+256] + bv[tid+256];
    h[i0] = o0; hb[i0] = __float2bfloat16(o0);
    h[i1] = o1; hb[i1] = __float2bfloat16(o1);
}

__global__ __launch_bounds__(256) void k_wconv(const float* __restrict__ a0, const float* __restrict__ a1,
                        const float* __restrict__ a2, const float* __restrict__ a3,
                        bf16* __restrict__ dst) {
    size_t i = ((size_t)blockIdx.x * 256 + threadIdx.x) * 8;
    const float* src; size_t off;
    if (i < 786432)       { src = a0; off = i; }
    else if (i < 1048576) { src = a1; off = i - 786432; }
    else if (i < 2097152) { src = a2; off = i - 1048576; }
    else                  { src = a3; off = i - 2097152; }
    short8 o;
#pragma unroll
    for (int j = 0; j < 8; j++) o[j] = __builtin_bit_cast(short, __float2bfloat16(src[off + j]));
    *(short8*)(void*)(dst + i) = o;
}

__global__ __launch_bounds__(256) void k_pool(const float* __restrict__ h, float* __restrict__ rep) {
    int b = blockIdx.x, d0 = blockIdx.y * 64;
    int t = threadIdx.x, dl = t & 63, sg = t >> 6;
    float acc = 0.0f;
    for (int s = sg*128; s < sg*128 + 128; s++)
        acc += h[((size_t)(b*CS + s))*CD + d0 + dl];
    __shared__ float red[256];
    red[t] = acc; __syncthreads();
    if (t < 64)
        rep[b*CD + d0 + dl] = (red[t] + red[t+64] + red[t+128] + red[t+192]) * (1.0f/CS);
}

__global__ void k_fc(const float* __restrict__ rep, const float* __restrict__ fcw,
                     const float* __restrict__ fcb, float* __restrict__ out) {
    int b = blockIdx.x, cc = blockIdx.y, l = threadIdx.x;
    float acc = 0.0f;
    for (int d = l; d < CD; d += 64) acc += rep[b*CD + d] * fcw[cc*CD + d];
    for (int o = 32; o > 0; o >>= 1) acc += __shfl_xor(acc, o);
    if (l == 0) out[b*CNC + cc] = acc + fcb[cc];
}

// ---------------------------------------------------------------------------
extern "C" void kernel_launch(void* const* d_in, const int* in_sizes, int n_in,
                              void* d_out, int out_size, void* d_ws, size_t ws_size,
                              hipStream_t stream) {
    const float* x   = (const float*)d_in[0];
    const float* rw1 = (const float*)d_in[1];
    const float* rb1 = (const float*)d_in[2];
    const float* rw2 = (const float*)d_in[3];
    const float* rb2 = (const float*)d_in[4];
    const float* emw = (const float*)d_in[5];
    const float* emb = (const float*)d_in[6];
    const float* aiw = (const float*)d_in[7];
    const float* aib = (const float*)d_in[8];
    const float* aow = (const float*)d_in[9];
    const float* aob = (const float*)d_in[10];
    const float* f1w = (const float*)d_in[11];
    const float* f1b = (const float*)d_in[12];
    const float* f2w = (const float*)d_in[13];
    const float* f2b = (const float*)d_in[14];
    const float* l1s = (const float*)d_in[15];
    const float* l1b = (const float*)d_in[16];
    const float* l2s = (const float*)d_in[17];
    const float* l2b = (const float*)d_in[18];
    const float* fcw = (const float*)d_in[19];
    const float* fcb = (const float*)d_in[20];
    float* out = (float*)d_out;

    char* p = (char*)d_ws;
    auto alloc = [&](size_t bytes) { char* r = p; p += (bytes + 255) & ~(size_t)255; return r; };
    bf16*  biasb = (bf16*)alloc((size_t)CB*CH*CS*CS*2);    // 16.78 MB
    float* h     = (float*)alloc((size_t)CB*CS*CD*4);      // 4.19 MB
    bf16*  hb    = (bf16*)alloc((size_t)CB*CS*CD*2);       // 2.10 MB
    bf16*  qkvb  = (bf16*)alloc((size_t)CB*CS*3*CD*2);     // 6.29 MB
    bf16*  vtb   = (bf16*)alloc((size_t)CB*CH*CDH*CS*2);   // 2.10 MB
    bf16*  attb  = (bf16*)alloc((size_t)CB*CS*CD*2);       // 2.10 MB
    float* tmp   = (float*)alloc((size_t)2*CB*CS*CD*4);    // 8.39 MB (2 split-K slabs)
    bf16*  ffb   = (bf16*)alloc((size_t)CB*CS*CDFF*2);     // 8.39 MB
    bf16*  wl    = (bf16*)alloc((size_t)3145728*2);        // 6.29 MB
    float* rep   = (float*)alloc((size_t)CB*CD*4);
    float* ts    = (float*)alloc(CB*CS*4);
    float* fs    = (float*)alloc(CB*CS*4);

    const int M = CB*CS;  // 2048
    float* tmp2 = tmp + (size_t)M*CD;

    k_standardize<<<dim3(CB,2), 256, 0, stream>>>(x, ts, fs);
    k_relpos<<<(CB*CS*CS)/256, 256, 0, stream>>>(ts, fs, rw1, rb1, rw2, rb2, biasb);
    k_embed<<<(M*CD)/256, 256, 0, stream>>>(x, emw, emb, h, hb);

    for (int l = 0; l < CL; l++) {
        const bf16* wl_aiw = wl;
        const bf16* wl_aow = wl + 786432;
        const bf16* wl_f1w = wl + 1048576;
        const bf16* wl_f2w = wl + 2097152;
        k_wconv<<<1536, 256, 0, stream>>>(aiw + (size_t)l*786432, aow + (size_t)l*262144,
                                          f1w + (size_t)l*1048576, f2w + (size_t)l*1048576, wl);
        // qkv = h @ aiw^T + aib ; V part written transposed into vtb
        k_mm_qkv<<<dim3(12,16), 256, 0, stream>>>(hb, wl_aiw, aib + (size_t)l*3*CD, qkvb, vtb);
        // fused attention
        k_attn_fused<<<dim3(CS/64, CB*CH), 256, 0, stream>>>(qkvb, vtb, biasb, attb);
        // out projection -> tmp (f32)
        k_mm<64,64,2,1><<<dim3(8,32), 256, 0, stream>>>(attb, CD, wl_aow, CD,
                                                        aob + (size_t)l*CD, nullptr, tmp, CD, CD);
        k_ln<1><<<M, 256, 0, stream>>>(h, tmp, nullptr, l1s + (size_t)l*CD, l1b + (size_t)l*CD, hb);
        // ff1 (relu)
        k_mm<128,128,1,1><<<dim3(16,16), 256, 0, stream>>>(hb, CD, wl_f1w, CD,
                                                           f1b + (size_t)l*CDFF, ffb, nullptr, CDFF, CD);
        // ff2 -> split-K=2 slabs tmp/tmp2 (f32)
        k_mm<64,64,2,2><<<dim3(8,32,2), 256, 0, stream>>>(ffb, CDFF, wl_f2w, CDFF,
                                                          f2b + (size_t)l*CD, nullptr, tmp, CD, CDFF);
        k_ln<2><<<M, 256, 0, stream>>>(h, tmp, tmp2, l2s + (size_t)l*CD, l2b + (size_t)l*CD, hb);
    }

    k_pool<<<dim3(CB, CD/64), 256, 0, stream>>>(h, rep);
    k_fc<<<dim3(CB, CNC), 64, 0, stream>>>(rep, fcw, fcb, out);
}

// Round 6
// 482.119 us; speedup vs baseline: 1.9596x; 1.1911x over previous
//
#include <hip/hip_runtime.h>
#include <hip/hip_bf16.h>
#include <stdint.h>

using short8 = __attribute__((ext_vector_type(8))) short;
using us4    = __attribute__((ext_vector_type(4))) unsigned short;
using f32x4  = __attribute__((ext_vector_type(4))) float;
using bf16   = __hip_bfloat16;

constexpr int CB=4, CS=512, CF=16, CD=512, CH=8, CL=6, CDFF=2048, CNC=12, CRPH=64, CDH=64;

__device__ inline void gload_lds16(const void* g, void* l) {
    __builtin_amdgcn_global_load_lds((const __attribute__((address_space(1))) void*)g,
                                     (__attribute__((address_space(3))) void*)l, 16, 0, 0);
}
__device__ inline float bfbits2f(unsigned short u) {
    return __uint_as_float(((uint32_t)u) << 16);
}
__device__ inline unsigned short f2bfbits(float f) {
    return __builtin_bit_cast(unsigned short, __float2bfloat16(f));
}

// ---------------------------------------------------------------------------
// BK=64 tile staging: LDS rows 128 B, XOR-swizzled (slot ^= row&7), linear dest +
// inverse-swizzled global source (both-sides rule).
template<int BM, int BN>
__device__ inline void stage_tile(const bf16* A, int lda, const bf16* W, int ldw, int k0,
                                  char* As, char* Bs) {
    constexpr int AC = BM/32, BC = BN/32;
    const int tid = threadIdx.x;
#pragma unroll
    for (int i = 0; i < AC; i++) {
        int s = i*256 + tid;
        int r = s >> 3, u = s & 7;
        const char* gp = (const char*)(A + (size_t)r*lda + k0) + ((u ^ (r&7))*16);
        gload_lds16(gp, As + (size_t)(s & ~63)*16);
    }
#pragma unroll
    for (int i = 0; i < BC; i++) {
        int s = i*256 + tid;
        int r = s >> 3, u = s & 7;
        const char* gp = (const char*)(W + (size_t)r*ldw + k0) + ((u ^ (r&7))*16);
        gload_lds16(gp, Bs + (size_t)(s & ~63)*16);
    }
}

template<int BM, int BN>
__device__ inline void compute_tile64(const char* As, const char* Bs,
                                      int wr, int wc, int c, int g,
                                      f32x4 (&acc)[BM/32][BN/32]) {
    constexpr int MR = BM/32, NR = BN/32;
#pragma unroll
    for (int kk = 0; kk < 2; kk++) {
        short8 af[MR], bfv[NR];
#pragma unroll
        for (int m = 0; m < MR; m++) {
            int row = wr*(BM/2) + m*16 + c;
            af[m] = *(const short8*)(As + row*128 + (((kk*4+g) ^ (row&7))*16));
        }
#pragma unroll
        for (int n = 0; n < NR; n++) {
            int row = wc*(BN/2) + n*16 + c;
            bfv[n] = *(const short8*)(Bs + row*128 + (((kk*4+g) ^ (row&7))*16));
        }
#pragma unroll
        for (int m = 0; m < MR; m++)
#pragma unroll
            for (int n = 0; n < NR; n++)
                acc[m][n] = __builtin_amdgcn_mfma_f32_16x16x32_bf16(af[m], bfv[n], acc[m][n], 0, 0, 0);
    }
}

// 2-phase pipelined GEMM core: stage(next) kept in flight across compute (counted vmcnt).
template<int BM, int BN>
__device__ inline void mm_core_pipe(const bf16* A, int lda, const bf16* W, int ldw, int K,
                                    char* smem, f32x4 (&acc)[BM/32][BN/32]) {
    constexpr int NLD = (BM+BN)/32;     // gload_lds issues per thread per stage
    const int tid = threadIdx.x;
    const int lane = tid & 63, wv = tid >> 6;
    const int wr = wv >> 1, wc = wv & 1;
    const int g = lane >> 4, c = lane & 15;
    char* Ac = smem;                 char* Bc = smem + BM*128;
    char* An = smem + (BM+BN)*128;   char* Bn = An + BM*128;

    stage_tile<BM,BN>(A, lda, W, ldw, 0, Ac, Bc);
    const int nk = K >> 6;
    for (int t = 0; t < nk; t++) {
        if (t + 1 < nk) {
            stage_tile<BM,BN>(A, lda, W, ldw, (t+1)*64, An, Bn);
            asm volatile("s_waitcnt vmcnt(%0)" :: "n"(NLD) : "memory");
        } else {
            asm volatile("s_waitcnt vmcnt(0)" ::: "memory");
        }
        __builtin_amdgcn_s_barrier();
        compute_tile64<BM,BN>(Ac, Bc, wr, wc, c, g, acc);
        __builtin_amdgcn_s_barrier();
        char* tp;
        tp = Ac; Ac = An; An = tp;
        tp = Bc; Bc = Bn; Bn = tp;
    }
}

// EPI: 0 = bf16+bias ; 1 = bf16+bias+relu ; 2 = f32+bias (bias only on kz==0)
template<int BM, int BN, int EPI, int KSPLIT>
__global__ __launch_bounds__(256) void k_mm(const bf16* __restrict__ A, int lda,
                                            const bf16* __restrict__ W, int ldw,
                                            const float* __restrict__ bias,
                                            bf16* __restrict__ Cb, float* __restrict__ Cf,
                                            int ldc, int K) {
    __shared__ char smem[2*(BM+BN)*128];
    const int bm = blockIdx.y * BM, bn = blockIdx.x * BN;
    const int kz = (KSPLIT > 1) ? blockIdx.z : 0;
    const int Kper = K / KSPLIT;
    f32x4 acc[BM/32][BN/32] = {};
    mm_core_pipe<BM,BN>(A + (size_t)bm*lda + kz*Kper, lda,
                        W + (size_t)bn*ldw + kz*Kper, ldw, Kper, smem, acc);
    const int lane = threadIdx.x & 63;
    const int wv = threadIdx.x >> 6, wr = wv>>1, wc = wv&1;
    float* Cfz = Cf + (size_t)kz * 2048 * ldc;
#pragma unroll
    for (int m = 0; m < BM/32; m++)
#pragma unroll
        for (int n = 0; n < BN/32; n++)
#pragma unroll
            for (int j = 0; j < 4; j++) {
                int row = bm + wr*(BM/2) + m*16 + (lane>>4)*4 + j;
                int col = bn + wc*(BN/2) + n*16 + (lane&15);
                float v = acc[m][n][j] + ((kz == 0) ? bias[col] : 0.0f);
                if (EPI == 1) v = fmaxf(v, 0.0f);
                if (EPI == 2) Cfz[(size_t)row*ldc + col] = v;
                else          Cb[(size_t)row*ldc + col] = __float2bfloat16(v);
            }
}

// qkv GEMM: writes Q,K into qkvb; V columns written transposed into vtb.
__global__ __launch_bounds__(256) void k_mm_qkv(const bf16* __restrict__ A,
                                                const bf16* __restrict__ W,
                                                const float* __restrict__ bias,
                                                bf16* __restrict__ qkvb,
                                                bf16* __restrict__ vtb) {
    constexpr int BM = 128, BN = 128;
    __shared__ char smem[2*(BM+BN)*128];
    const int bm = blockIdx.y * BM, bn = blockIdx.x * BN;
    f32x4 acc[4][4] = {};
    mm_core_pipe<BM,BN>(A + (size_t)bm*CD, CD, W + (size_t)bn*CD, CD, CD, smem, acc);
    const int lane = threadIdx.x & 63;
    const int wv = threadIdx.x >> 6, wr = wv>>1, wc = wv&1;
    const int g = lane >> 4, c = lane & 15;
    if (bn < 2*CD) {
#pragma unroll
        for (int m = 0; m < 4; m++)
#pragma unroll
            for (int n = 0; n < 4; n++)
#pragma unroll
                for (int j = 0; j < 4; j++) {
                    int row = bm + wr*64 + m*16 + g*4 + j;
                    int col = bn + wc*64 + n*16 + c;
                    qkvb[(size_t)row*(3*CD) + col] = __float2bfloat16(acc[m][n][j] + bias[col]);
                }
    } else {
#pragma unroll
        for (int m = 0; m < 4; m++)
#pragma unroll
            for (int n = 0; n < 4; n++) {
                int row0 = bm + wr*64 + m*16 + g*4;
                int col  = bn + wc*64 + n*16 + c;
                int z = (row0 >> 9)*8 + ((col - 2*CD) >> 6);
                int d = (col - 2*CD) & 63;
                int s0 = row0 & 511;
                float bcol = bias[col];
                us4 o;
#pragma unroll
                for (int j = 0; j < 4; j++) o[j] = f2bfbits(acc[m][n][j] + bcol);
                *(us4*)(vtb + ((size_t)z*CDH + d)*CS + s0) = o;
            }
    }
}

// ---------------------------------------------------------------------------
// Fused attention with 2-phase K/V pipeline: per (b,h, 64-q tile):
// S^T = K@Q^T (+bias), online softmax (q lane-local), P -> LDS swizzled, O^T = Vt@P^T.
__global__ __launch_bounds__(256) void k_attn_fused(const bf16* __restrict__ qkv,
                                                    const bf16* __restrict__ vt,
                                                    const bf16* __restrict__ bias,
                                                    bf16* __restrict__ att) {
    __shared__ char Kbuf[2][16384];
    __shared__ char Vbuf[2][16384];
    __shared__ char Ps[16384];

    const int z = blockIdx.y, b = z >> 3, h = z & 7;
    const int qbase = blockIdx.x * 64;
    const int tid = threadIdx.x, l = tid & 63, w = tid >> 6;
    const int g = l >> 4, c = l & 15, swz = l & 7;
    const int q_global = qbase + w*16 + c;

    const bf16* qrow = qkv + ((size_t)(b*CS + q_global))*(3*CD) + h*CDH;
    short8 bq0 = *(const short8*)(qrow + g*8);
    short8 bq1 = *(const short8*)(qrow + 32 + g*8);
    const bf16* brow = bias + ((size_t)z*CS + q_global)*CS;

    float mrun = -1e30f, lsum = 0.0f;
    f32x4 accO[4] = {};
    char* Pb = Ps + w*4096;

    auto stageKV = [&](int kv0, char* Ks, char* Vs) {
#pragma unroll
        for (int i = 0; i < 4; i++) {
            int s = i*256 + tid;
            int r = s >> 3, u = s & 7;
            const bf16* gk = qkv + ((size_t)(b*CS + kv0 + r))*(3*CD) + CD + h*CDH + ((u ^ (r&7)) * 8);
            gload_lds16(gk, Ks + (size_t)(s & ~63)*16);
        }
#pragma unroll
        for (int i = 0; i < 4; i++) {
            int s = i*256 + tid;
            int d = s >> 4, u = s & 15;
            const bf16* gv = vt + ((size_t)(z*CDH + d))*CS + kv0 + ((u ^ (d&7)) * 8);
            gload_lds16(gv, Vs + (size_t)(s & ~63)*16);
        }
    };

    char* Kc = Kbuf[0]; char* Vc = Vbuf[0];
    char* Kn = Kbuf[1]; char* Vn = Vbuf[1];
    stageKV(0, Kc, Vc);

    for (int t = 0; t < 4; t++) {
        int kv0 = t * 128;
        if (t < 3) {
            stageKV(kv0 + 128, Kn, Vn);
            asm volatile("s_waitcnt vmcnt(8)" ::: "memory");
        } else {
            asm volatile("s_waitcnt vmcnt(0)" ::: "memory");
        }
        __builtin_amdgcn_s_barrier();

        float sv[8][4];
        float tmax = -1e30f;
#pragma unroll
        for (int n = 0; n < 8; n++) {
            int row = n*16 + c;
            short8 af0 = *(const short8*)(Kc + row*128 + ((g    ^ swz) * 16));
            short8 af1 = *(const short8*)(Kc + row*128 + (((4+g) ^ swz) * 16));
            f32x4 a = {};
            a = __builtin_amdgcn_mfma_f32_16x16x32_bf16(af0, bq0, a, 0, 0, 0);
            a = __builtin_amdgcn_mfma_f32_16x16x32_bf16(af1, bq1, a, 0, 0, 0);
            us4 b4 = *(const us4*)(brow + kv0 + n*16 + g*4);
#pragma unroll
            for (int j = 0; j < 4; j++) {
                sv[n][j] = a[j] * 0.125f + bfbits2f(b4[j]);
                tmax = fmaxf(tmax, sv[n][j]);
            }
        }
        tmax = fmaxf(tmax, __shfl_xor(tmax, 16));
        tmax = fmaxf(tmax, __shfl_xor(tmax, 32));
        float mnew = fmaxf(mrun, tmax);
        float corr = __expf(mrun - mnew);
        float tsum = 0.0f;
#pragma unroll
        for (int n = 0; n < 8; n++)
#pragma unroll
            for (int j = 0; j < 4; j++) {
                float e = __expf(sv[n][j] - mnew);
                sv[n][j] = e;
                tsum += e;
            }
        tsum += __shfl_xor(tsum, 16);
        tsum += __shfl_xor(tsum, 32);
        lsum = lsum * corr + tsum;
        mrun = mnew;
#pragma unroll
        for (int n2 = 0; n2 < 4; n2++)
#pragma unroll
            for (int j = 0; j < 4; j++) accO[n2][j] *= corr;

#pragma unroll
        for (int n = 0; n < 8; n++) {
            us4 pk;
#pragma unroll
            for (int j = 0; j < 4; j++) pk[j] = f2bfbits(sv[n][j]);
            *(us4*)(Pb + c*256 + ((n*32 + g*8) ^ (swz << 4))) = pk;
        }

#pragma unroll
        for (int n2 = 0; n2 < 4; n2++) {
            int d = n2*16 + c;
#pragma unroll
            for (int kk = 0; kk < 4; kk++) {
                short8 av = *(const short8*)(Vc + d*256 + (((kk*4 + g) ^ swz) * 16));
                short8 bp = *(const short8*)(Pb + c*256 + (((kk*64 + g*16) ^ (swz << 4))));
                accO[n2] = __builtin_amdgcn_mfma_f32_16x16x32_bf16(av, bp, accO[n2], 0, 0, 0);
            }
        }
        __builtin_amdgcn_s_barrier();
        char* tp;
        tp = Kc; Kc = Kn; Kn = tp;
        tp = Vc; Vc = Vn; Vn = tp;
    }

    float inv = 1.0f / lsum;
    bf16* orow = att + ((size_t)(b*CS + q_global))*CD + h*CDH;
#pragma unroll
    for (int n2 = 0; n2 < 4; n2++) {
        us4 o;
#pragma unroll
        for (int j = 0; j < 4; j++) o[j] = f2bfbits(accO[n2][j] * inv);
        *(us4*)(orow + n2*16 + g*4) = o;
    }
}

// ---------------------------------------------------------------------------
__global__ void k_standardize(const float* __restrict__ x, float* __restrict__ ts,
                              float* __restrict__ fs) {
    int b = blockIdx.x, ch = blockIdx.y, tid = threadIdx.x;
    __shared__ float red[256];
    float v0 = x[(b*CS + tid)*CF + ch];
    float v1 = x[(b*CS + tid + 256)*CF + ch];
    red[tid] = v0 + v1; __syncthreads();
    for (int w = 128; w > 0; w >>= 1) { if (tid < w) red[tid] += red[tid+w]; __syncthreads(); }
    float mean = red[0] * (1.0f/CS); __syncthreads();
    float d0 = v0-mean, d1 = v1-mean;
    red[tid] = d0*d0 + d1*d1; __syncthreads();
    for (int w = 128; w > 0; w >>= 1) { if (tid < w) red[tid] += red[tid+w]; __syncthreads(); }
    float inv = rsqrtf(red[0]*(1.0f/CS) + 1e-6f);
    float* o = ch == 0 ? ts : fs;
    o[b*CS + tid] = d0*inv; o[b*CS + tid + 256] = d1*inv;
}

__global__ __launch_bounds__(256) void k_relpos(const float* __restrict__ ts, const float* __restrict__ fs,
                         const float* __restrict__ w1, const float* __restrict__ b1,
                         const float* __restrict__ w2, const float* __restrict__ b2,
                         bf16* __restrict__ bias) {
    int idx = blockIdx.x * 256 + threadIdx.x;
    int j = idx & (CS-1), i = (idx >> 9) & (CS-1), b = idx >> 18;
    float dt = ts[b*CS + i] - ts[b*CS + j];
    float df = fs[b*CS + i] - fs[b*CS + j];
    float acc[CH];
#pragma unroll
    for (int h = 0; h < CH; h++) acc[h] = b2[h];
    for (int r = 0; r < CRPH; r++) {
        float hd = fmaxf(w1[r*2]*dt + w1[r*2+1]*df + b1[r], 0.0f);
#pragma unroll
        for (int h = 0; h < CH; h++) acc[h] += w2[h*CRPH + r] * hd;
    }
#pragma unroll
    for (int h = 0; h < CH; h++) {
        float v = fminf(fmaxf(acc[h], -5.0f), 5.0f);
        bias[((size_t)(b*CH + h)*CS + i)*CS + j] = __float2bfloat16(v);
    }
}

__global__ __launch_bounds__(256) void k_embed(const float* __restrict__ x, const float* __restrict__ w,
                        const float* __restrict__ bv, float* __restrict__ h, bf16* __restrict__ hb) {
    int idx = blockIdx.x * 256 + threadIdx.x;
    int d = idx & (CD-1), m = idx >> 9;
    const float* xr = x + m*CF;
    const float* wr = w + d*CF;
    float acc = bv[d];
#pragma unroll
    for (int f = 0; f < CF; f++) acc += xr[f]*wr[f];
    h[idx] = acc; hb[idx] = __float2bfloat16(acc);
}

// residual + LN; NADD extra f32 slabs summed in
template<int NADD>
__global__ __launch_bounds__(256) void k_ln(float* __restrict__ h, const float* __restrict__ a0,
                     const float* __restrict__ a1,
                     const float* __restrict__ s, const float* __restrict__ bv, bf16* __restrict__ hb) {
    int row = blockIdx.x, tid = threadIdx.x;
    __shared__ float red[256];
    size_t i0 = (size_t)row*CD + tid, i1 = i0 + 256;
    float v0 = h[i0] + a0[i0];
    float v1 = h[i1] + a0[i1];
    if (NADD == 2) { v0 += a1[i0]; v1 += a1[i1]; }
    red[tid] = v0 + v1; __syncthreads();
    for (int w = 128; w > 0; w >>= 1) { if (tid < w) red[tid] += red[tid+w]; __syncthreads(); }
    float mean = red[0] * (1.0f/CD); __syncthreads();
    float d0 = v0-mean, d1 = v1-mean;
    red[tid] = d0*d0 + d1*d1; __syncthreads();
    for (int w = 128; w > 0; w >>= 1) { if (tid < w) red[tid] += red[tid+w]; __syncthreads(); }
    float inv = rsqrtf(red[0]*(1.0f/CD) + 1e-5f);
    float o0 = d0*inv*s[tid] + bv[tid];
    float o1 = d1*inv*s[tid+256] + bv[tid+256];
    h[i0] = o0; hb[i0] = __float2bfloat16(o0);
    h[i1] = o1; hb[i1] = __float2bfloat16(o1);
}

// per-layer weight conversion (fallback path)
__global__ __launch_bounds__(256) void k_wconv(const float* __restrict__ a0, const float* __restrict__ a1,
                        const float* __restrict__ a2, const float* __restrict__ a3,
                        bf16* __restrict__ dst) {
    size_t i = ((size_t)blockIdx.x * 256 + threadIdx.x) * 8;
    const float* src; size_t off;
    if (i < 786432)       { src = a0; off = i; }
    else if (i < 1048576) { src = a1; off = i - 786432; }
    else if (i < 2097152) { src = a2; off = i - 1048576; }
    else                  { src = a3; off = i - 2097152; }
    short8 o;
#pragma unroll
    for (int j = 0; j < 8; j++) o[j] = __builtin_bit_cast(short, __float2bfloat16(src[off + j]));
    *(short8*)(void*)(dst + i) = o;
}

// one-shot conversion of all 6 layers' weights
__global__ __launch_bounds__(256) void k_wconv_all(const float* __restrict__ aiw, const float* __restrict__ aow,
                        const float* __restrict__ f1w, const float* __restrict__ f2w,
                        bf16* __restrict__ dst) {
    int lyr = blockIdx.y;
    size_t i = ((size_t)blockIdx.x * 256 + threadIdx.x) * 8;
    const float* src; size_t off;
    if (i < 786432)       { src = aiw + (size_t)lyr* 786432; off = i; }
    else if (i < 1048576) { src = aow + (size_t)lyr* 262144; off = i - 786432; }
    else if (i < 2097152) { src = f1w + (size_t)lyr*1048576; off = i - 1048576; }
    else                  { src = f2w + (size_t)lyr*1048576; off = i - 2097152; }
    short8 o;
#pragma unroll
    for (int j = 0; j < 8; j++) o[j] = __builtin_bit_cast(short, __float2bfloat16(src[off + j]));
    *(short8*)(void*)(dst + (size_t)lyr*3145728 + i) = o;
}

__global__ __launch_bounds__(256) void k_pool(const float* __restrict__ h, float* __restrict__ rep) {
    int b = blockIdx.x, d0 = blockIdx.y * 64;
    int t = threadIdx.x, dl = t & 63, sg = t >> 6;
    float acc = 0.0f;
    for (int s = sg*128; s < sg*128 + 128; s++)
        acc += h[((size_t)(b*CS + s))*CD + d0 + dl];
    __shared__ float red[256];
    red[t] = acc; __syncthreads();
    if (t < 64)
        rep[b*CD + d0 + dl] = (red[t] + red[t+64] + red[t+128] + red[t+192]) * (1.0f/CS);
}

__global__ void k_fc(const float* __restrict__ rep, const float* __restrict__ fcw,
                     const float* __restrict__ fcb, float* __restrict__ out) {
    int b = blockIdx.x, cc = blockIdx.y, l = threadIdx.x;
    float acc = 0.0f;
    for (int d = l; d < CD; d += 64) acc += rep[b*CD + d] * fcw[cc*CD + d];
    for (int o = 32; o > 0; o >>= 1) acc += __shfl_xor(acc, o);
    if (l == 0) out[b*CNC + cc] = acc + fcb[cc];
}

// ---------------------------------------------------------------------------
extern "C" void kernel_launch(void* const* d_in, const int* in_sizes, int n_in,
                              void* d_out, int out_size, void* d_ws, size_t ws_size,
                              hipStream_t stream) {
    const float* x   = (const float*)d_in[0];
    const float* rw1 = (const float*)d_in[1];
    const float* rb1 = (const float*)d_in[2];
    const float* rw2 = (const float*)d_in[3];
    const float* rb2 = (const float*)d_in[4];
    const float* emw = (const float*)d_in[5];
    const float* emb = (const float*)d_in[6];
    const float* aiw = (const float*)d_in[7];
    const float* aib = (const float*)d_in[8];
    const float* aow = (const float*)d_in[9];
    const float* aob = (const float*)d_in[10];
    const float* f1w = (const float*)d_in[11];
    const float* f1b = (const float*)d_in[12];
    const float* f2w = (const float*)d_in[13];
    const float* f2b = (const float*)d_in[14];
    const float* l1s = (const float*)d_in[15];
    const float* l1b = (const float*)d_in[16];
    const float* l2s = (const float*)d_in[17];
    const float* l2b = (const float*)d_in[18];
    const float* fcw = (const float*)d_in[19];
    const float* fcb = (const float*)d_in[20];
    float* out = (float*)d_out;

    char* p = (char*)d_ws;
    auto alloc = [&](size_t bytes) { char* r = p; p += (bytes + 255) & ~(size_t)255; return r; };
    bf16*  biasb = (bf16*)alloc((size_t)CB*CH*CS*CS*2);    // 16.78 MB
    float* h     = (float*)alloc((size_t)CB*CS*CD*4);      // 4.19 MB
    bf16*  hb    = (bf16*)alloc((size_t)CB*CS*CD*2);       // 2.10 MB
    bf16*  qkvb  = (bf16*)alloc((size_t)CB*CS*3*CD*2);     // 6.29 MB
    bf16*  vtb   = (bf16*)alloc((size_t)CB*CH*CDH*CS*2);   // 2.10 MB
    bf16*  attb  = (bf16*)alloc((size_t)CB*CS*CD*2);       // 2.10 MB
    float* tmp   = (float*)alloc((size_t)2*CB*CS*CD*4);    // 8.39 MB (2 split-K slabs)
    bf16*  ffb   = (bf16*)alloc((size_t)CB*CS*CDFF*2);     // 8.39 MB
    bf16*  wl    = (bf16*)alloc((size_t)3145728*2);        // 6.29 MB (per-layer fallback)
    float* rep   = (float*)alloc((size_t)CB*CD*4);
    float* ts    = (float*)alloc(CB*CS*4);
    float* fs    = (float*)alloc(CB*CS*4);

    // one-shot weight buffer if workspace permits (deterministic given fixed ws_size)
    size_t used = (size_t)(p - (char*)d_ws);
    const size_t WLE = 3145728;   // elements per layer (aiw|aow|f1w|f2w)
    bool oneshot = (ws_size > used) && ((ws_size - used) >= (size_t)CL*WLE*2 + 256);
    bf16* wlall = (bf16*)alloc(oneshot ? (size_t)CL*WLE*2 : 0);

    const int M = CB*CS;  // 2048
    float* tmp2 = tmp + (size_t)M*CD;

    k_standardize<<<dim3(CB,2), 256, 0, stream>>>(x, ts, fs);
    k_relpos<<<(CB*CS*CS)/256, 256, 0, stream>>>(ts, fs, rw1, rb1, rw2, rb2, biasb);
    k_embed<<<(M*CD)/256, 256, 0, stream>>>(x, emw, emb, h, hb);
    if (oneshot)
        k_wconv_all<<<dim3(1536, CL), 256, 0, stream>>>(aiw, aow, f1w, f2w, wlall);

    for (int l = 0; l < CL; l++) {
        const bf16* wbase = oneshot ? (wlall + (size_t)l*WLE) : wl;
        if (!oneshot)
            k_wconv<<<1536, 256, 0, stream>>>(aiw + (size_t)l*786432, aow + (size_t)l*262144,
                                              f1w + (size_t)l*1048576, f2w + (size_t)l*1048576, wl);
        const bf16* wl_aiw = wbase;
        const bf16* wl_aow = wbase + 786432;
        const bf16* wl_f1w = wbase + 1048576;
        const bf16* wl_f2w = wbase + 2097152;
        // qkv = h @ aiw^T + aib ; V part written transposed into vtb
        k_mm_qkv<<<dim3(12,16), 256, 0, stream>>>(hb, wl_aiw, aib + (size_t)l*3*CD, qkvb, vtb);
        // fused attention
        k_attn_fused<<<dim3(CS/64, CB*CH), 256, 0, stream>>>(qkvb, vtb, biasb, attb);
        // out projection -> tmp (f32)
        k_mm<64,64,2,1><<<dim3(8,32), 256, 0, stream>>>(attb, CD, wl_aow, CD,
                                                        aob + (size_t)l*CD, nullptr, tmp, CD, CD);
        k_ln<1><<<M, 256, 0, stream>>>(h, tmp, nullptr, l1s + (size_t)l*CD, l1b + (size_t)l*CD, hb);
        // ff1 (relu)
        k_mm<128,128,1,1><<<dim3(16,16), 256, 0, stream>>>(hb, CD, wl_f1w, CD,
                                                           f1b + (size_t)l*CDFF, ffb, nullptr, CDFF, CD);
        // ff2 -> split-K=2 slabs tmp/tmp2 (f32)
        k_mm<64,64,2,2><<<dim3(8,32,2), 256, 0, stream>>>(ffb, CDFF, wl_f2w, CDFF,
                                                          f2b + (size_t)l*CD, nullptr, tmp, CD, CDFF);
        k_ln<2><<<M, 256, 0, stream>>>(h, tmp, tmp2, l2s + (size_t)l*CD, l2b + (size_t)l*CD, hb);
    }

    k_pool<<<dim3(CB, CD/64), 256, 0, stream>>>(h, rep);
    k_fc<<<dim3(CB, CNC), 64, 0, stream>>>(rep, fcw, fcb, out);
}

// Round 7
// 456.938 us; speedup vs baseline: 2.0676x; 1.0551x over previous
//
#include <hip/hip_runtime.h>
#include <hip/hip_bf16.h>
#include <stdint.h>

using short8 = __attribute__((ext_vector_type(8))) short;
using us4    = __attribute__((ext_vector_type(4))) unsigned short;
using f32x4  = __attribute__((ext_vector_type(4))) float;
using bf16   = __hip_bfloat16;

constexpr int CB=4, CS=512, CF=16, CD=512, CH=8, CL=6, CDFF=2048, CNC=12, CRPH=64, CDH=64;

__device__ inline void gload_lds16(const void* g, void* l) {
    __builtin_amdgcn_global_load_lds((const __attribute__((address_space(1))) void*)g,
                                     (__attribute__((address_space(3))) void*)l, 16, 0, 0);
}
__device__ inline float bfbits2f(unsigned short u) {
    return __uint_as_float(((uint32_t)u) << 16);
}
__device__ inline unsigned short f2bfbits(float f) {
    return __builtin_bit_cast(unsigned short, __float2bfloat16(f));
}

// ---------------------------------------------------------------------------
// GEMM geometry: TPB=256 -> 2x2 wave grid; TPB=512 -> 2x4 wave grid.
template<int BM, int BN, int TPB>
struct MMGeom {
    static constexpr int WC  = (TPB == 512) ? 4 : 2;
    static constexpr int WR  = (TPB/64)/WC;
    static constexpr int RS  = BM/WR;      // rows per wave
    static constexpr int CSP = BN/WC;      // cols per wave
    static constexpr int MR  = RS/16;
    static constexpr int NR  = CSP/16;
    static constexpr int NLD = (BM+BN)*128/(TPB*16);  // gload issues per thread/stage
};

// BK=64 tile staging: LDS rows 128 B, XOR-swizzled (slot ^= row&7), linear dest +
// inverse-swizzled global source (both-sides rule).
template<int BM, int BN, int TPB>
__device__ inline void stage_tile(const bf16* A, int lda, const bf16* W, int ldw, int k0,
                                  char* As, char* Bs) {
    constexpr int AC = (BM*128)/(TPB*16);
    constexpr int BC = (BN*128)/(TPB*16);
    const int tid = threadIdx.x;
#pragma unroll
    for (int i = 0; i < AC; i++) {
        int s = i*TPB + tid;
        int r = s >> 3, u = s & 7;
        const char* gp = (const char*)(A + (size_t)r*lda + k0) + ((u ^ (r&7))*16);
        gload_lds16(gp, As + (size_t)(s & ~63)*16);
    }
#pragma unroll
    for (int i = 0; i < BC; i++) {
        int s = i*TPB + tid;
        int r = s >> 3, u = s & 7;
        const char* gp = (const char*)(W + (size_t)r*ldw + k0) + ((u ^ (r&7))*16);
        gload_lds16(gp, Bs + (size_t)(s & ~63)*16);
    }
}

template<int BM, int BN, int TPB>
__device__ inline void compute_tile64(const char* As, const char* Bs,
                                      int wr, int wc, int c, int g,
                                      f32x4 (&acc)[MMGeom<BM,BN,TPB>::MR][MMGeom<BM,BN,TPB>::NR]) {
    using G = MMGeom<BM,BN,TPB>;
#pragma unroll
    for (int kk = 0; kk < 2; kk++) {
        short8 af[G::MR], bfv[G::NR];
#pragma unroll
        for (int m = 0; m < G::MR; m++) {
            int row = wr*G::RS + m*16 + c;
            af[m] = *(const short8*)(As + row*128 + (((kk*4+g) ^ (row&7))*16));
        }
#pragma unroll
        for (int n = 0; n < G::NR; n++) {
            int row = wc*G::CSP + n*16 + c;
            bfv[n] = *(const short8*)(Bs + row*128 + (((kk*4+g) ^ (row&7))*16));
        }
#pragma unroll
        for (int m = 0; m < G::MR; m++)
#pragma unroll
            for (int n = 0; n < G::NR; n++)
                acc[m][n] = __builtin_amdgcn_mfma_f32_16x16x32_bf16(af[m], bfv[n], acc[m][n], 0, 0, 0);
    }
}

// 2-phase pipelined GEMM core (counted vmcnt keeps next-tile loads in flight).
template<int BM, int BN, int TPB>
__device__ inline void mm_core_pipe(const bf16* A, int lda, const bf16* W, int ldw, int K,
                                    char* smem,
                                    f32x4 (&acc)[MMGeom<BM,BN,TPB>::MR][MMGeom<BM,BN,TPB>::NR]) {
    using G = MMGeom<BM,BN,TPB>;
    const int tid = threadIdx.x;
    const int lane = tid & 63, wv = tid >> 6;
    const int wr = wv / G::WC, wc = wv % G::WC;
    const int g = lane >> 4, c = lane & 15;
    char* Ac = smem;                 char* Bc = smem + BM*128;
    char* An = smem + (BM+BN)*128;   char* Bn = An + BM*128;

    stage_tile<BM,BN,TPB>(A, lda, W, ldw, 0, Ac, Bc);
    const int nk = K >> 6;
    for (int t = 0; t < nk; t++) {
        if (t + 1 < nk) {
            stage_tile<BM,BN,TPB>(A, lda, W, ldw, (t+1)*64, An, Bn);
            asm volatile("s_waitcnt vmcnt(%0)" :: "n"(G::NLD) : "memory");
        } else {
            asm volatile("s_waitcnt vmcnt(0)" ::: "memory");
        }
        __builtin_amdgcn_s_barrier();
        compute_tile64<BM,BN,TPB>(Ac, Bc, wr, wc, c, g, acc);
        __builtin_amdgcn_s_barrier();
        char* tp;
        tp = Ac; Ac = An; An = tp;
        tp = Bc; Bc = Bn; Bn = tp;
    }
}

// EPI: 0 = bf16+bias ; 1 = bf16+bias+relu ; 2 = f32+bias (bias only on kz==0)
template<int BM, int BN, int EPI, int KSPLIT, int TPB>
__global__ __launch_bounds__(TPB) void k_mm(const bf16* __restrict__ A, int lda,
                                            const bf16* __restrict__ W, int ldw,
                                            const float* __restrict__ bias,
                                            bf16* __restrict__ Cb, float* __restrict__ Cf,
                                            int ldc, int K) {
    using G = MMGeom<BM,BN,TPB>;
    __shared__ char smem[2*(BM+BN)*128];
    const int bm = blockIdx.y * BM, bn = blockIdx.x * BN;
    const int kz = (KSPLIT > 1) ? blockIdx.z : 0;
    const int Kper = K / KSPLIT;
    f32x4 acc[G::MR][G::NR] = {};
    mm_core_pipe<BM,BN,TPB>(A + (size_t)bm*lda + kz*Kper, lda,
                            W + (size_t)bn*ldw + kz*Kper, ldw, Kper, smem, acc);
    const int lane = threadIdx.x & 63, wv = threadIdx.x >> 6;
    const int wr = wv / G::WC, wc = wv % G::WC;
    const int g = lane >> 4, c = lane & 15;
    float* Cfz = Cf + (size_t)kz * 2048 * ldc;
#pragma unroll
    for (int m = 0; m < G::MR; m++)
#pragma unroll
        for (int n = 0; n < G::NR; n++)
#pragma unroll
            for (int j = 0; j < 4; j++) {
                int row = bm + wr*G::RS + m*16 + g*4 + j;
                int col = bn + wc*G::CSP + n*16 + c;
                float v = acc[m][n][j] + ((kz == 0) ? bias[col] : 0.0f);
                if (EPI == 1) v = fmaxf(v, 0.0f);
                if (EPI == 2) Cfz[(size_t)row*ldc + col] = v;
                else          Cb[(size_t)row*ldc + col] = __float2bfloat16(v);
            }
}

// qkv GEMM: writes Q,K into qkvb; V columns written transposed into vtb.
__global__ __launch_bounds__(512) void k_mm_qkv(const bf16* __restrict__ A,
                                                const bf16* __restrict__ W,
                                                const float* __restrict__ bias,
                                                bf16* __restrict__ qkvb,
                                                bf16* __restrict__ vtb) {
    constexpr int BM = 128, BN = 128, TPB = 512;
    using G = MMGeom<BM,BN,TPB>;
    __shared__ char smem[2*(BM+BN)*128];
    const int bm = blockIdx.y * BM, bn = blockIdx.x * BN;
    f32x4 acc[G::MR][G::NR] = {};
    mm_core_pipe<BM,BN,TPB>(A + (size_t)bm*CD, CD, W + (size_t)bn*CD, CD, CD, smem, acc);
    const int lane = threadIdx.x & 63, wv = threadIdx.x >> 6;
    const int wr = wv / G::WC, wc = wv % G::WC;
    const int g = lane >> 4, c = lane & 15;
    if (bn < 2*CD) {
#pragma unroll
        for (int m = 0; m < G::MR; m++)
#pragma unroll
            for (int n = 0; n < G::NR; n++)
#pragma unroll
                for (int j = 0; j < 4; j++) {
                    int row = bm + wr*G::RS + m*16 + g*4 + j;
                    int col = bn + wc*G::CSP + n*16 + c;
                    qkvb[(size_t)row*(3*CD) + col] = __float2bfloat16(acc[m][n][j] + bias[col]);
                }
    } else {
#pragma unroll
        for (int m = 0; m < G::MR; m++)
#pragma unroll
            for (int n = 0; n < G::NR; n++) {
                int row0 = bm + wr*G::RS + m*16 + g*4;
                int col  = bn + wc*G::CSP + n*16 + c;
                int z = (row0 >> 9)*8 + ((col - 2*CD) >> 6);
                int d = (col - 2*CD) & 63;
                int s0 = row0 & 511;
                float bcol = bias[col];
                us4 o;
#pragma unroll
                for (int j = 0; j < 4; j++) o[j] = f2bfbits(acc[m][n][j] + bcol);
                *(us4*)(vtb + ((size_t)z*CDH + d)*CS + s0) = o;
            }
    }
}

// ---------------------------------------------------------------------------
// Fused attention with 2-phase K/V pipeline + defer-max (THR=8).
__global__ __launch_bounds__(256) void k_attn_fused(const bf16* __restrict__ qkv,
                                                    const bf16* __restrict__ vt,
                                                    const bf16* __restrict__ bias,
                                                    bf16* __restrict__ att) {
    __shared__ char Kbuf[2][16384];
    __shared__ char Vbuf[2][16384];
    __shared__ char Ps[16384];

    const int z = blockIdx.y, b = z >> 3, h = z & 7;
    const int qbase = blockIdx.x * 64;
    const int tid = threadIdx.x, l = tid & 63, w = tid >> 6;
    const int g = l >> 4, c = l & 15, swz = l & 7;
    const int q_global = qbase + w*16 + c;

    const bf16* qrow = qkv + ((size_t)(b*CS + q_global))*(3*CD) + h*CDH;
    short8 bq0 = *(const short8*)(qrow + g*8);
    short8 bq1 = *(const short8*)(qrow + 32 + g*8);
    const bf16* brow = bias + ((size_t)z*CS + q_global)*CS;

    float mrun = -1e30f, lsum = 0.0f;
    f32x4 accO[4] = {};
    char* Pb = Ps + w*4096;

    auto stageKV = [&](int kv0, char* Ks, char* Vs) {
#pragma unroll
        for (int i = 0; i < 4; i++) {
            int s = i*256 + tid;
            int r = s >> 3, u = s & 7;
            const bf16* gk = qkv + ((size_t)(b*CS + kv0 + r))*(3*CD) + CD + h*CDH + ((u ^ (r&7)) * 8);
            gload_lds16(gk, Ks + (size_t)(s & ~63)*16);
        }
#pragma unroll
        for (int i = 0; i < 4; i++) {
            int s = i*256 + tid;
            int d = s >> 4, u = s & 15;
            const bf16* gv = vt + ((size_t)(z*CDH + d))*CS + kv0 + ((u ^ (d&7)) * 8);
            gload_lds16(gv, Vs + (size_t)(s & ~63)*16);
        }
    };

    char* Kc = Kbuf[0]; char* Vc = Vbuf[0];
    char* Kn = Kbuf[1]; char* Vn = Vbuf[1];
    stageKV(0, Kc, Vc);

    for (int t = 0; t < 4; t++) {
        int kv0 = t * 128;
        if (t < 3) {
            stageKV(kv0 + 128, Kn, Vn);
            asm volatile("s_waitcnt vmcnt(8)" ::: "memory");
        } else {
            asm volatile("s_waitcnt vmcnt(0)" ::: "memory");
        }
        __builtin_amdgcn_s_barrier();

        float sv[8][4];
        float tmax = -1e30f;
#pragma unroll
        for (int n = 0; n < 8; n++) {
            int row = n*16 + c;
            short8 af0 = *(const short8*)(Kc + row*128 + ((g    ^ swz) * 16));
            short8 af1 = *(const short8*)(Kc + row*128 + (((4+g) ^ swz) * 16));
            f32x4 a = {};
            a = __builtin_amdgcn_mfma_f32_16x16x32_bf16(af0, bq0, a, 0, 0, 0);
            a = __builtin_amdgcn_mfma_f32_16x16x32_bf16(af1, bq1, a, 0, 0, 0);
            us4 b4 = *(const us4*)(brow + kv0 + n*16 + g*4);
#pragma unroll
            for (int j = 0; j < 4; j++) {
                sv[n][j] = a[j] * 0.125f + bfbits2f(b4[j]);
                tmax = fmaxf(tmax, sv[n][j]);
            }
        }
        tmax = fmaxf(tmax, __shfl_xor(tmax, 16));
        tmax = fmaxf(tmax, __shfl_xor(tmax, 32));
        // defer-max: only rescale when some q-row grew by > 8
        if (!__all(tmax - mrun <= 8.0f)) {
            float mnew = fmaxf(mrun, tmax);
            float corr = __expf(mrun - mnew);
            lsum *= corr;
#pragma unroll
            for (int n2 = 0; n2 < 4; n2++)
#pragma unroll
                for (int j = 0; j < 4; j++) accO[n2][j] *= corr;
            mrun = mnew;
        }
        float tsum = 0.0f;
#pragma unroll
        for (int n = 0; n < 8; n++)
#pragma unroll
            for (int j = 0; j < 4; j++) {
                float e = __expf(sv[n][j] - mrun);
                sv[n][j] = e;
                tsum += e;
            }
        tsum += __shfl_xor(tsum, 16);
        tsum += __shfl_xor(tsum, 32);
        lsum += tsum;

#pragma unroll
        for (int n = 0; n < 8; n++) {
            us4 pk;
#pragma unroll
            for (int j = 0; j < 4; j++) pk[j] = f2bfbits(sv[n][j]);
            *(us4*)(Pb + c*256 + ((n*32 + g*8) ^ (swz << 4))) = pk;
        }

#pragma unroll
        for (int n2 = 0; n2 < 4; n2++) {
            int d = n2*16 + c;
#pragma unroll
            for (int kk = 0; kk < 4; kk++) {
                short8 av = *(const short8*)(Vc + d*256 + (((kk*4 + g) ^ swz) * 16));
                short8 bp = *(const short8*)(Pb + c*256 + (((kk*64 + g*16) ^ (swz << 4))));
                accO[n2] = __builtin_amdgcn_mfma_f32_16x16x32_bf16(av, bp, accO[n2], 0, 0, 0);
            }
        }
        __builtin_amdgcn_s_barrier();
        char* tp;
        tp = Kc; Kc = Kn; Kn = tp;
        tp = Vc; Vc = Vn; Vn = tp;
    }

    float inv = 1.0f / lsum;
    bf16* orow = att + ((size_t)(b*CS + q_global))*CD + h*CDH;
#pragma unroll
    for (int n2 = 0; n2 < 4; n2++) {
        us4 o;
#pragma unroll
        for (int j = 0; j < 4; j++) o[j] = f2bfbits(accO[n2][j] * inv);
        *(us4*)(orow + n2*16 + g*4) = o;
    }
}

// ---------------------------------------------------------------------------
__global__ void k_standardize(const float* __restrict__ x, float* __restrict__ ts,
                              float* __restrict__ fs) {
    int b = blockIdx.x, ch = blockIdx.y, tid = threadIdx.x;
    __shared__ float red[256];
    float v0 = x[(b*CS + tid)*CF + ch];
    float v1 = x[(b*CS + tid + 256)*CF + ch];
    red[tid] = v0 + v1; __syncthreads();
    for (int w = 128; w > 0; w >>= 1) { if (tid < w) red[tid] += red[tid+w]; __syncthreads(); }
    float mean = red[0] * (1.0f/CS); __syncthreads();
    float d0 = v0-mean, d1 = v1-mean;
    red[tid] = d0*d0 + d1*d1; __syncthreads();
    for (int w = 128; w > 0; w >>= 1) { if (tid < w) red[tid] += red[tid+w]; __syncthreads(); }
    float inv = rsqrtf(red[0]*(1.0f/CS) + 1e-6f);
    float* o = ch == 0 ? ts : fs;
    o[b*CS + tid] = d0*inv; o[b*CS + tid + 256] = d1*inv;
}

__global__ __launch_bounds__(256) void k_relpos(const float* __restrict__ ts, const float* __restrict__ fs,
                         const float* __restrict__ w1, const float* __restrict__ b1,
                         const float* __restrict__ w2, const float* __restrict__ b2,
                         bf16* __restrict__ bias) {
    int idx = blockIdx.x * 256 + threadIdx.x;
    int j = idx & (CS-1), i = (idx >> 9) & (CS-1), b = idx >> 18;
    float dt = ts[b*CS + i] - ts[b*CS + j];
    float df = fs[b*CS + i] - fs[b*CS + j];
    float acc[CH];
#pragma unroll
    for (int h = 0; h < CH; h++) acc[h] = b2[h];
    for (int r = 0; r < CRPH; r++) {
        float hd = fmaxf(w1[r*2]*dt + w1[r*2+1]*df + b1[r], 0.0f);
#pragma unroll
        for (int h = 0; h < CH; h++) acc[h] += w2[h*CRPH + r] * hd;
    }
#pragma unroll
    for (int h = 0; h < CH; h++) {
        float v = fminf(fmaxf(acc[h], -5.0f), 5.0f);
        bias[((size_t)(b*CH + h)*CS + i)*CS + j] = __float2bfloat16(v);
    }
}

__global__ __launch_bounds__(256) void k_embed(const float* __restrict__ x, const float* __restrict__ w,
                        const float* __restrict__ bv, float* __restrict__ h, bf16* __restrict__ hb) {
    int idx = blockIdx.x * 256 + threadIdx.x;
    int d = idx & (CD-1), m = idx >> 9;
    const float* xr = x + m*CF;
    const float* wr = w + d*CF;
    float acc = bv[d];
#pragma unroll
    for (int f = 0; f < CF; f++) acc += xr[f]*wr[f];
    h[idx] = acc; hb[idx] = __float2bfloat16(acc);
}

// residual + LN, wave-per-row, vectorized, no LDS. grid = M/4, 256 threads.
template<int NADD>
__global__ __launch_bounds__(256) void k_ln(float* __restrict__ h, const float* __restrict__ a0,
                     const float* __restrict__ a1,
                     const float* __restrict__ s, const float* __restrict__ bv, bf16* __restrict__ hb) {
    const int w = threadIdx.x >> 6, l = threadIdx.x & 63;
    const int row = blockIdx.x*4 + w;
    float* hr = h + (size_t)row*CD;
    const float* ar = a0 + (size_t)row*CD;
    const float* a1r = (NADD == 2) ? (a1 + (size_t)row*CD) : nullptr;

    float v[8];
    {
        float4 h0 = ((const float4*)hr)[l*2],  h1 = ((const float4*)hr)[l*2+1];
        float4 b0 = ((const float4*)ar)[l*2],  b1 = ((const float4*)ar)[l*2+1];
        v[0]=h0.x+b0.x; v[1]=h0.y+b0.y; v[2]=h0.z+b0.z; v[3]=h0.w+b0.w;
        v[4]=h1.x+b1.x; v[5]=h1.y+b1.y; v[6]=h1.z+b1.z; v[7]=h1.w+b1.w;
        if (NADD == 2) {
            float4 c0 = ((const float4*)a1r)[l*2], c1 = ((const float4*)a1r)[l*2+1];
            v[0]+=c0.x; v[1]+=c0.y; v[2]+=c0.z; v[3]+=c0.w;
            v[4]+=c1.x; v[5]+=c1.y; v[6]+=c1.z; v[7]+=c1.w;
        }
    }
    float sum = 0.f, sq = 0.f;
#pragma unroll
    for (int i = 0; i < 8; i++) { sum += v[i]; sq += v[i]*v[i]; }
#pragma unroll
    for (int off = 1; off < 64; off <<= 1) {
        sum += __shfl_xor(sum, off);
        sq  += __shfl_xor(sq, off);
    }
    float mean = sum * (1.0f/CD);
    float var  = sq * (1.0f/CD) - mean*mean;
    float rstd = rsqrtf(var + 1e-5f);

    float4 s0 = ((const float4*)s)[l*2],  s1 = ((const float4*)s)[l*2+1];
    float4 g0 = ((const float4*)bv)[l*2], g1 = ((const float4*)bv)[l*2+1];
    float o[8];
    o[0]=(v[0]-mean)*rstd*s0.x+g0.x; o[1]=(v[1]-mean)*rstd*s0.y+g0.y;
    o[2]=(v[2]-mean)*rstd*s0.z+g0.z; o[3]=(v[3]-mean)*rstd*s0.w+g0.w;
    o[4]=(v[4]-mean)*rstd*s1.x+g1.x; o[5]=(v[5]-mean)*rstd*s1.y+g1.y;
    o[6]=(v[6]-mean)*rstd*s1.z+g1.z; o[7]=(v[7]-mean)*rstd*s1.w+g1.w;

    ((float4*)hr)[l*2]   = make_float4(o[0],o[1],o[2],o[3]);
    ((float4*)hr)[l*2+1] = make_float4(o[4],o[5],o[6],o[7]);
    short8 ob;
#pragma unroll
    for (int i = 0; i < 8; i++) ob[i] = (short)f2bfbits(o[i]);
    *(short8*)(hb + (size_t)row*CD + l*8) = ob;
}

// per-layer weight conversion (fallback path)
__global__ __launch_bounds__(256) void k_wconv(const float* __restrict__ a0, const float* __restrict__ a1,
                        const float* __restrict__ a2, const float* __restrict__ a3,
                        bf16* __restrict__ dst) {
    size_t i = ((size_t)blockIdx.x * 256 + threadIdx.x) * 8;
    const float* src; size_t off;
    if (i < 786432)       { src = a0; off = i; }
    else if (i < 1048576) { src = a1; off = i - 786432; }
    else if (i < 2097152) { src = a2; off = i - 1048576; }
    else                  { src = a3; off = i - 2097152; }
    short8 o;
#pragma unroll
    for (int j = 0; j < 8; j++) o[j] = __builtin_bit_cast(short, __float2bfloat16(src[off + j]));
    *(short8*)(void*)(dst + i) = o;
}

// one-shot conversion of all 6 layers' weights
__global__ __launch_bounds__(256) void k_wconv_all(const float* __restrict__ aiw, const float* __restrict__ aow,
                        const float* __restrict__ f1w, const float* __restrict__ f2w,
                        bf16* __restrict__ dst) {
    int lyr = blockIdx.y;
    size_t i = ((size_t)blockIdx.x * 256 + threadIdx.x) * 8;
    const float* src; size_t off;
    if (i < 786432)       { src = aiw + (size_t)lyr* 786432; off = i; }
    else if (i < 1048576) { src = aow + (size_t)lyr* 262144; off = i - 786432; }
    else if (i < 2097152) { src = f1w + (size_t)lyr*1048576; off = i - 1048576; }
    else                  { src = f2w + (size_t)lyr*1048576; off = i - 2097152; }
    short8 o;
#pragma unroll
    for (int j = 0; j < 8; j++) o[j] = __builtin_bit_cast(short, __float2bfloat16(src[off + j]));
    *(short8*)(void*)(dst + (size_t)lyr*3145728 + i) = o;
}

__global__ __launch_bounds__(256) void k_pool(const float* __restrict__ h, float* __restrict__ rep) {
    int b = blockIdx.x, d0 = blockIdx.y * 64;
    int t = threadIdx.x, dl = t & 63, sg = t >> 6;
    float acc = 0.0f;
    for (int s = sg*128; s < sg*128 + 128; s++)
        acc += h[((size_t)(b*CS + s))*CD + d0 + dl];
    __shared__ float red[256];
    red[t] = acc; __syncthreads();
    if (t < 64)
        rep[b*CD + d0 + dl] = (red[t] + red[t+64] + red[t+128] + red[t+192]) * (1.0f/CS);
}

__global__ void k_fc(const float* __restrict__ rep, const float* __restrict__ fcw,
                     const float* __restrict__ fcb, float* __restrict__ out) {
    int b = blockIdx.x, cc = blockIdx.y, l = threadIdx.x;
    float acc = 0.0f;
    for (int d = l; d < CD; d += 64) acc += rep[b*CD + d] * fcw[cc*CD + d];
    for (int o = 32; o > 0; o >>= 1) acc += __shfl_xor(acc, o);
    if (l == 0) out[b*CNC + cc] = acc + fcb[cc];
}

// ---------------------------------------------------------------------------
extern "C" void kernel_launch(void* const* d_in, const int* in_sizes, int n_in,
                              void* d_out, int out_size, void* d_ws, size_t ws_size,
                              hipStream_t stream) {
    const float* x   = (const float*)d_in[0];
    const float* rw1 = (const float*)d_in[1];
    const float* rb1 = (const float*)d_in[2];
    const float* rw2 = (const float*)d_in[3];
    const float* rb2 = (const float*)d_in[4];
    const float* emw = (const float*)d_in[5];
    const float* emb = (const float*)d_in[6];
    const float* aiw = (const float*)d_in[7];
    const float* aib = (const float*)d_in[8];
    const float* aow = (const float*)d_in[9];
    const float* aob = (const float*)d_in[10];
    const float* f1w = (const float*)d_in[11];
    const float* f1b = (const float*)d_in[12];
    const float* f2w = (const float*)d_in[13];
    const float* f2b = (const float*)d_in[14];
    const float* l1s = (const float*)d_in[15];
    const float* l1b = (const float*)d_in[16];
    const float* l2s = (const float*)d_in[17];
    const float* l2b = (const float*)d_in[18];
    const float* fcw = (const float*)d_in[19];
    const float* fcb = (const float*)d_in[20];
    float* out = (float*)d_out;

    char* p = (char*)d_ws;
    auto alloc = [&](size_t bytes) { char* r = p; p += (bytes + 255) & ~(size_t)255; return r; };
    bf16*  biasb = (bf16*)alloc((size_t)CB*CH*CS*CS*2);    // 16.78 MB
    float* h     = (float*)alloc((size_t)CB*CS*CD*4);      // 4.19 MB
    bf16*  hb    = (bf16*)alloc((size_t)CB*CS*CD*2);       // 2.10 MB
    bf16*  qkvb  = (bf16*)alloc((size_t)CB*CS*3*CD*2);     // 6.29 MB
    bf16*  vtb   = (bf16*)alloc((size_t)CB*CH*CDH*CS*2);   // 2.10 MB
    bf16*  attb  = (bf16*)alloc((size_t)CB*CS*CD*2);       // 2.10 MB
    float* tmp   = (float*)alloc((size_t)2*CB*CS*CD*4);    // 8.39 MB (2 split-K slabs)
    bf16*  ffb   = (bf16*)alloc((size_t)CB*CS*CDFF*2);     // 8.39 MB
    bf16*  wl    = (bf16*)alloc((size_t)3145728*2);        // 6.29 MB (per-layer fallback)
    float* rep   = (float*)alloc((size_t)CB*CD*4);
    float* ts    = (float*)alloc(CB*CS*4);
    float* fs    = (float*)alloc(CB*CS*4);

    // one-shot weight buffer if workspace permits (deterministic given fixed ws_size)
    size_t used = (size_t)(p - (char*)d_ws);
    const size_t WLE = 3145728;   // elements per layer (aiw|aow|f1w|f2w)
    bool oneshot = (ws_size > used) && ((ws_size - used) >= (size_t)CL*WLE*2 + 256);
    bf16* wlall = (bf16*)alloc(oneshot ? (size_t)CL*WLE*2 : 0);

    const int M = CB*CS;  // 2048
    float* tmp2 = tmp + (size_t)M*CD;

    k_standardize<<<dim3(CB,2), 256, 0, stream>>>(x, ts, fs);
    k_relpos<<<(CB*CS*CS)/256, 256, 0, stream>>>(ts, fs, rw1, rb1, rw2, rb2, biasb);
    k_embed<<<(M*CD)/256, 256, 0, stream>>>(x, emw, emb, h, hb);
    if (oneshot)
        k_wconv_all<<<dim3(1536, CL), 256, 0, stream>>>(aiw, aow, f1w, f2w, wlall);

    for (int l = 0; l < CL; l++) {
        const bf16* wbase = oneshot ? (wlall + (size_t)l*WLE) : wl;
        if (!oneshot)
            k_wconv<<<1536, 256, 0, stream>>>(aiw + (size_t)l*786432, aow + (size_t)l*262144,
                                              f1w + (size_t)l*1048576, f2w + (size_t)l*1048576, wl);
        const bf16* wl_aiw = wbase;
        const bf16* wl_aow = wbase + 786432;
        const bf16* wl_f1w = wbase + 1048576;
        const bf16* wl_f2w = wbase + 2097152;
        // qkv = h @ aiw^T + aib ; V part written transposed into vtb
        k_mm_qkv<<<dim3(12,16), 512, 0, stream>>>(hb, wl_aiw, aib + (size_t)l*3*CD, qkvb, vtb);
        // fused attention
        k_attn_fused<<<dim3(CS/64, CB*CH), 256, 0, stream>>>(qkvb, vtb, biasb, attb);
        // out projection -> tmp (f32)
        k_mm<64,64,2,1,512><<<dim3(8,32), 512, 0, stream>>>(attb, CD, wl_aow, CD,
                                                            aob + (size_t)l*CD, nullptr, tmp, CD, CD);
        k_ln<1><<<M/4, 256, 0, stream>>>(h, tmp, nullptr, l1s + (size_t)l*CD, l1b + (size_t)l*CD, hb);
        // ff1 (relu)
        k_mm<128,128,1,1,512><<<dim3(16,16), 512, 0, stream>>>(hb, CD, wl_f1w, CD,
                                                               f1b + (size_t)l*CDFF, ffb, nullptr, CDFF, CD);
        // ff2 -> split-K=2 slabs tmp/tmp2 (f32)
        k_mm<64,64,2,2,512><<<dim3(8,32,2), 512, 0, stream>>>(ffb, CDFF, wl_f2w, CDFF,
                                                              f2b + (size_t)l*CD, nullptr, tmp, CD, CDFF);
        k_ln<2><<<M/4, 256, 0, stream>>>(h, tmp, tmp2, l2s + (size_t)l*CD, l2b + (size_t)l*CD, hb);
    }

    k_pool<<<dim3(CB, CD/64), 256, 0, stream>>>(h, rep);
    k_fc<<<dim3(CB, CNC), 64, 0, stream>>>(rep, fcw, fcb, out);
}

// Round 8
// 456.437 us; speedup vs baseline: 2.0698x; 1.0011x over previous
//
#include <hip/hip_runtime.h>
#include <hip/hip_bf16.h>
#include <stdint.h>

using short8 = __attribute__((ext_vector_type(8))) short;
using us4    = __attribute__((ext_vector_type(4))) unsigned short;
using f32x4  = __attribute__((ext_vector_type(4))) float;
using bf16   = __hip_bfloat16;

constexpr int CB=4, CS=512, CF=16, CD=512, CH=8, CL=6, CDFF=2048, CNC=12, CRPH=64, CDH=64;

__device__ inline void gload_lds16(const void* g, void* l) {
    __builtin_amdgcn_global_load_lds((const __attribute__((address_space(1))) void*)g,
                                     (__attribute__((address_space(3))) void*)l, 16, 0, 0);
}
__device__ inline float bfbits2f(unsigned short u) {
    return __uint_as_float(((uint32_t)u) << 16);
}
__device__ inline unsigned short f2bfbits(float f) {
    return __builtin_bit_cast(unsigned short, __float2bfloat16(f));
}

// ---------------------------------------------------------------------------
// GEMM geometry: TPB=256 -> 2x2 wave grid; TPB=512 -> 2x4 wave grid.
template<int BM, int BN, int TPB>
struct MMGeom {
    static constexpr int WC  = (TPB == 512) ? 4 : 2;
    static constexpr int WR  = (TPB/64)/WC;
    static constexpr int RS  = BM/WR;      // rows per wave
    static constexpr int CSP = BN/WC;      // cols per wave
    static constexpr int MR  = RS/16;
    static constexpr int NR  = CSP/16;
    static constexpr int NLD = (BM+BN)*128/(TPB*16);  // gload issues per thread/stage
};

// BK=64 tile staging: LDS rows 128 B, XOR-swizzled (slot ^= row&7), linear dest +
// inverse-swizzled global source (both-sides rule).
template<int BM, int BN, int TPB>
__device__ inline void stage_tile(const bf16* A, int lda, const bf16* W, int ldw, int k0,
                                  char* As, char* Bs) {
    constexpr int AC = (BM*128)/(TPB*16);
    constexpr int BC = (BN*128)/(TPB*16);
    const int tid = threadIdx.x;
#pragma unroll
    for (int i = 0; i < AC; i++) {
        int s = i*TPB + tid;
        int r = s >> 3, u = s & 7;
        const char* gp = (const char*)(A + (size_t)r*lda + k0) + ((u ^ (r&7))*16);
        gload_lds16(gp, As + (size_t)(s & ~63)*16);
    }
#pragma unroll
    for (int i = 0; i < BC; i++) {
        int s = i*TPB + tid;
        int r = s >> 3, u = s & 7;
        const char* gp = (const char*)(W + (size_t)r*ldw + k0) + ((u ^ (r&7))*16);
        gload_lds16(gp, Bs + (size_t)(s & ~63)*16);
    }
}

template<int BM, int BN, int TPB>
__device__ inline void compute_tile64(const char* As, const char* Bs,
                                      int wr, int wc, int c, int g,
                                      f32x4 (&acc)[MMGeom<BM,BN,TPB>::MR][MMGeom<BM,BN,TPB>::NR]) {
    using G = MMGeom<BM,BN,TPB>;
#pragma unroll
    for (int kk = 0; kk < 2; kk++) {
        short8 af[G::MR], bfv[G::NR];
#pragma unroll
        for (int m = 0; m < G::MR; m++) {
            int row = wr*G::RS + m*16 + c;
            af[m] = *(const short8*)(As + row*128 + (((kk*4+g) ^ (row&7))*16));
        }
#pragma unroll
        for (int n = 0; n < G::NR; n++) {
            int row = wc*G::CSP + n*16 + c;
            bfv[n] = *(const short8*)(Bs + row*128 + (((kk*4+g) ^ (row&7))*16));
        }
#pragma unroll
        for (int m = 0; m < G::MR; m++)
#pragma unroll
            for (int n = 0; n < G::NR; n++)
                acc[m][n] = __builtin_amdgcn_mfma_f32_16x16x32_bf16(af[m], bfv[n], acc[m][n], 0, 0, 0);
    }
}

// 3-stage pipelined GEMM core: tile t+2 issued while computing tile t.
// Steady-state wait vmcnt(2*NLD); tail NLD -> 0.  LDS ring of 3 buffers.
template<int BM, int BN, int TPB>
__device__ inline void mm_core_pipe(const bf16* A, int lda, const bf16* W, int ldw, int K,
                                    char* smem,
                                    f32x4 (&acc)[MMGeom<BM,BN,TPB>::MR][MMGeom<BM,BN,TPB>::NR]) {
    using G = MMGeom<BM,BN,TPB>;
    constexpr int SSZ = (BM+BN)*128;
    const int tid = threadIdx.x;
    const int lane = tid & 63, wv = tid >> 6;
    const int wr = wv / G::WC, wc = wv % G::WC;
    const int g = lane >> 4, c = lane & 15;
    char* b0 = smem;            // compute buffer
    char* b1 = smem + SSZ;      // next
    char* b2 = smem + 2*SSZ;    // stage target (t+2)

    const int nk = K >> 6;
    stage_tile<BM,BN,TPB>(A, lda, W, ldw, 0, b0, b0 + BM*128);
    if (nk > 1) stage_tile<BM,BN,TPB>(A, lda, W, ldw, 64, b1, b1 + BM*128);

    for (int t = 0; t < nk; t++) {
        if (t + 2 < nk) {
            stage_tile<BM,BN,TPB>(A, lda, W, ldw, (t+2)*64, b2, b2 + BM*128);
            asm volatile("s_waitcnt vmcnt(%0)" :: "n"(2*G::NLD) : "memory");
        } else if (t + 1 < nk) {
            asm volatile("s_waitcnt vmcnt(%0)" :: "n"(G::NLD) : "memory");
        } else {
            asm volatile("s_waitcnt vmcnt(0)" ::: "memory");
        }
        __builtin_amdgcn_s_barrier();
        compute_tile64<BM,BN,TPB>(b0, b0 + BM*128, wr, wc, c, g, acc);
        __builtin_amdgcn_s_barrier();
        char* tp = b0; b0 = b1; b1 = b2; b2 = tp;
    }
}

// EPI: 0 = bf16+bias ; 1 = bf16+bias+relu ; 2 = f32+bias (bias only on kz==0)
template<int BM, int BN, int EPI, int KSPLIT, int TPB>
__global__ __launch_bounds__(TPB) void k_mm(const bf16* __restrict__ A, int lda,
                                            const bf16* __restrict__ W, int ldw,
                                            const float* __restrict__ bias,
                                            bf16* __restrict__ Cb, float* __restrict__ Cf,
                                            int ldc, int K) {
    using G = MMGeom<BM,BN,TPB>;
    __shared__ char smem[3*(BM+BN)*128];
    const int bm = blockIdx.y * BM, bn = blockIdx.x * BN;
    const int kz = (KSPLIT > 1) ? blockIdx.z : 0;
    const int Kper = K / KSPLIT;
    f32x4 acc[G::MR][G::NR] = {};
    mm_core_pipe<BM,BN,TPB>(A + (size_t)bm*lda + kz*Kper, lda,
                            W + (size_t)bn*ldw + kz*Kper, ldw, Kper, smem, acc);
    const int lane = threadIdx.x & 63, wv = threadIdx.x >> 6;
    const int wr = wv / G::WC, wc = wv % G::WC;
    const int g = lane >> 4, c = lane & 15;
    float* Cfz = Cf + (size_t)kz * 2048 * ldc;
#pragma unroll
    for (int m = 0; m < G::MR; m++)
#pragma unroll
        for (int n = 0; n < G::NR; n++)
#pragma unroll
            for (int j = 0; j < 4; j++) {
                int row = bm + wr*G::RS + m*16 + g*4 + j;
                int col = bn + wc*G::CSP + n*16 + c;
                float v = acc[m][n][j] + ((kz == 0) ? bias[col] : 0.0f);
                if (EPI == 1) v = fmaxf(v, 0.0f);
                if (EPI == 2) Cfz[(size_t)row*ldc + col] = v;
                else          Cb[(size_t)row*ldc + col] = __float2bfloat16(v);
            }
}

// qkv GEMM: writes Q,K into qkvb; V columns written transposed into vtb.
__global__ __launch_bounds__(512) void k_mm_qkv(const bf16* __restrict__ A,
                                                const bf16* __restrict__ W,
                                                const float* __restrict__ bias,
                                                bf16* __restrict__ qkvb,
                                                bf16* __restrict__ vtb) {
    constexpr int BM = 128, BN = 128, TPB = 512;
    using G = MMGeom<BM,BN,TPB>;
    __shared__ char smem[3*(BM+BN)*128];
    const int bm = blockIdx.y * BM, bn = blockIdx.x * BN;
    f32x4 acc[G::MR][G::NR] = {};
    mm_core_pipe<BM,BN,TPB>(A + (size_t)bm*CD, CD, W + (size_t)bn*CD, CD, CD, smem, acc);
    const int lane = threadIdx.x & 63, wv = threadIdx.x >> 6;
    const int wr = wv / G::WC, wc = wv % G::WC;
    const int g = lane >> 4, c = lane & 15;
    if (bn < 2*CD) {
#pragma unroll
        for (int m = 0; m < G::MR; m++)
#pragma unroll
            for (int n = 0; n < G::NR; n++)
#pragma unroll
                for (int j = 0; j < 4; j++) {
                    int row = bm + wr*G::RS + m*16 + g*4 + j;
                    int col = bn + wc*G::CSP + n*16 + c;
                    qkvb[(size_t)row*(3*CD) + col] = __float2bfloat16(acc[m][n][j] + bias[col]);
                }
    } else {
#pragma unroll
        for (int m = 0; m < G::MR; m++)
#pragma unroll
            for (int n = 0; n < G::NR; n++) {
                int row0 = bm + wr*G::RS + m*16 + g*4;
                int col  = bn + wc*G::CSP + n*16 + c;
                int z = (row0 >> 9)*8 + ((col - 2*CD) >> 6);
                int d = (col - 2*CD) & 63;
                int s0 = row0 & 511;
                float bcol = bias[col];
                us4 o;
#pragma unroll
                for (int j = 0; j < 4; j++) o[j] = f2bfbits(acc[m][n][j] + bcol);
                *(us4*)(vtb + ((size_t)z*CDH + d)*CS + s0) = o;
            }
    }
}

// ---------------------------------------------------------------------------
// Fused attention with 2-phase K/V pipeline + defer-max (THR=8).
__global__ __launch_bounds__(256) void k_attn_fused(const bf16* __restrict__ qkv,
                                                    const bf16* __restrict__ vt,
                                                    const bf16* __restrict__ bias,
                                                    bf16* __restrict__ att) {
    __shared__ char Kbuf[2][16384];
    __shared__ char Vbuf[2][16384];
    __shared__ char Ps[16384];

    const int z = blockIdx.y, b = z >> 3, h = z & 7;
    const int qbase = blockIdx.x * 64;
    const int tid = threadIdx.x, l = tid & 63, w = tid >> 6;
    const int g = l >> 4, c = l & 15, swz = l & 7;
    const int q_global = qbase + w*16 + c;

    const bf16* qrow = qkv + ((size_t)(b*CS + q_global))*(3*CD) + h*CDH;
    short8 bq0 = *(const short8*)(qrow + g*8);
    short8 bq1 = *(const short8*)(qrow + 32 + g*8);
    const bf16* brow = bias + ((size_t)z*CS + q_global)*CS;

    float mrun = -1e30f, lsum = 0.0f;
    f32x4 accO[4] = {};
    char* Pb = Ps + w*4096;

    auto stageKV = [&](int kv0, char* Ks, char* Vs) {
#pragma unroll
        for (int i = 0; i < 4; i++) {
            int s = i*256 + tid;
            int r = s >> 3, u = s & 7;
            const bf16* gk = qkv + ((size_t)(b*CS + kv0 + r))*(3*CD) + CD + h*CDH + ((u ^ (r&7)) * 8);
            gload_lds16(gk, Ks + (size_t)(s & ~63)*16);
        }
#pragma unroll
        for (int i = 0; i < 4; i++) {
            int s = i*256 + tid;
            int d = s >> 4, u = s & 15;
            const bf16* gv = vt + ((size_t)(z*CDH + d))*CS + kv0 + ((u ^ (d&7)) * 8);
            gload_lds16(gv, Vs + (size_t)(s & ~63)*16);
        }
    };

    char* Kc = Kbuf[0]; char* Vc = Vbuf[0];
    char* Kn = Kbuf[1]; char* Vn = Vbuf[1];
    stageKV(0, Kc, Vc);

    for (int t = 0; t < 4; t++) {
        int kv0 = t * 128;
        if (t < 3) {
            stageKV(kv0 + 128, Kn, Vn);
            asm volatile("s_waitcnt vmcnt(8)" ::: "memory");
        } else {
            asm volatile("s_waitcnt vmcnt(0)" ::: "memory");
        }
        __builtin_amdgcn_s_barrier();

        float sv[8][4];
        float tmax = -1e30f;
#pragma unroll
        for (int n = 0; n < 8; n++) {
            int row = n*16 + c;
            short8 af0 = *(const short8*)(Kc + row*128 + ((g    ^ swz) * 16));
            short8 af1 = *(const short8*)(Kc + row*128 + (((4+g) ^ swz) * 16));
            f32x4 a = {};
            a = __builtin_amdgcn_mfma_f32_16x16x32_bf16(af0, bq0, a, 0, 0, 0);
            a = __builtin_amdgcn_mfma_f32_16x16x32_bf16(af1, bq1, a, 0, 0, 0);
            us4 b4 = *(const us4*)(brow + kv0 + n*16 + g*4);
#pragma unroll
            for (int j = 0; j < 4; j++) {
                sv[n][j] = a[j] * 0.125f + bfbits2f(b4[j]);
                tmax = fmaxf(tmax, sv[n][j]);
            }
        }
        tmax = fmaxf(tmax, __shfl_xor(tmax, 16));
        tmax = fmaxf(tmax, __shfl_xor(tmax, 32));
        // defer-max: only rescale when some q-row grew by > 8
        if (!__all(tmax - mrun <= 8.0f)) {
            float mnew = fmaxf(mrun, tmax);
            float corr = __expf(mrun - mnew);
            lsum *= corr;
#pragma unroll
            for (int n2 = 0; n2 < 4; n2++)
#pragma unroll
                for (int j = 0; j < 4; j++) accO[n2][j] *= corr;
            mrun = mnew;
        }
        float tsum = 0.0f;
#pragma unroll
        for (int n = 0; n < 8; n++)
#pragma unroll
            for (int j = 0; j < 4; j++) {
                float e = __expf(sv[n][j] - mrun);
                sv[n][j] = e;
                tsum += e;
            }
        tsum += __shfl_xor(tsum, 16);
        tsum += __shfl_xor(tsum, 32);
        lsum += tsum;

#pragma unroll
        for (int n = 0; n < 8; n++) {
            us4 pk;
#pragma unroll
            for (int j = 0; j < 4; j++) pk[j] = f2bfbits(sv[n][j]);
            *(us4*)(Pb + c*256 + ((n*32 + g*8) ^ (swz << 4))) = pk;
        }

#pragma unroll
        for (int n2 = 0; n2 < 4; n2++) {
            int d = n2*16 + c;
#pragma unroll
            for (int kk = 0; kk < 4; kk++) {
                short8 av = *(const short8*)(Vc + d*256 + (((kk*4 + g) ^ swz) * 16));
                short8 bp = *(const short8*)(Pb + c*256 + (((kk*64 + g*16) ^ (swz << 4))));
                accO[n2] = __builtin_amdgcn_mfma_f32_16x16x32_bf16(av, bp, accO[n2], 0, 0, 0);
            }
        }
        __builtin_amdgcn_s_barrier();
        char* tp;
        tp = Kc; Kc = Kn; Kn = tp;
        tp = Vc; Vc = Vn; Vn = tp;
    }

    float inv = 1.0f / lsum;
    bf16* orow = att + ((size_t)(b*CS + q_global))*CD + h*CDH;
#pragma unroll
    for (int n2 = 0; n2 < 4; n2++) {
        us4 o;
#pragma unroll
        for (int j = 0; j < 4; j++) o[j] = f2bfbits(accO[n2][j] * inv);
        *(us4*)(orow + n2*16 + g*4) = o;
    }
}

// ---------------------------------------------------------------------------
__global__ void k_standardize(const float* __restrict__ x, float* __restrict__ ts,
                              float* __restrict__ fs) {
    int b = blockIdx.x, ch = blockIdx.y, tid = threadIdx.x;
    __shared__ float red[256];
    float v0 = x[(b*CS + tid)*CF + ch];
    float v1 = x[(b*CS + tid + 256)*CF + ch];
    red[tid] = v0 + v1; __syncthreads();
    for (int w = 128; w > 0; w >>= 1) { if (tid < w) red[tid] += red[tid+w]; __syncthreads(); }
    float mean = red[0] * (1.0f/CS); __syncthreads();
    float d0 = v0-mean, d1 = v1-mean;
    red[tid] = d0*d0 + d1*d1; __syncthreads();
    for (int w = 128; w > 0; w >>= 1) { if (tid < w) red[tid] += red[tid+w]; __syncthreads(); }
    float inv = rsqrtf(red[0]*(1.0f/CS) + 1e-6f);
    float* o = ch == 0 ? ts : fs;
    o[b*CS + tid] = d0*inv; o[b*CS + tid + 256] = d1*inv;
}

__global__ __launch_bounds__(256) void k_relpos(const float* __restrict__ ts, const float* __restrict__ fs,
                         const float* __restrict__ w1, const float* __restrict__ b1,
                         const float* __restrict__ w2, const float* __restrict__ b2,
                         bf16* __restrict__ bias) {
    int idx = blockIdx.x * 256 + threadIdx.x;
    int j = idx & (CS-1), i = (idx >> 9) & (CS-1), b = idx >> 18;
    float dt = ts[b*CS + i] - ts[b*CS + j];
    float df = fs[b*CS + i] - fs[b*CS + j];
    float acc[CH];
#pragma unroll
    for (int h = 0; h < CH; h++) acc[h] = b2[h];
    for (int r = 0; r < CRPH; r++) {
        float hd = fmaxf(w1[r*2]*dt + w1[r*2+1]*df + b1[r], 0.0f);
#pragma unroll
        for (int h = 0; h < CH; h++) acc[h] += w2[h*CRPH + r] * hd;
    }
#pragma unroll
    for (int h = 0; h < CH; h++) {
        float v = fminf(fmaxf(acc[h], -5.0f), 5.0f);
        bias[((size_t)(b*CH + h)*CS + i)*CS + j] = __float2bfloat16(v);
    }
}

__global__ __launch_bounds__(256) void k_embed(const float* __restrict__ x, const float* __restrict__ w,
                        const float* __restrict__ bv, float* __restrict__ h, bf16* __restrict__ hb) {
    int idx = blockIdx.x * 256 + threadIdx.x;
    int d = idx & (CD-1), m = idx >> 9;
    const float* xr = x + m*CF;
    const float* wr = w + d*CF;
    float acc = bv[d];
#pragma unroll
    for (int f = 0; f < CF; f++) acc += xr[f]*wr[f];
    h[idx] = acc; hb[idx] = __float2bfloat16(acc);
}

// residual + LN, wave-per-row, vectorized, no LDS. grid = M/4, 256 threads.
template<int NADD>
__global__ __launch_bounds__(256) void k_ln(float* __restrict__ h, const float* __restrict__ a0,
                     const float* __restrict__ a1,
                     const float* __restrict__ s, const float* __restrict__ bv, bf16* __restrict__ hb) {
    const int w = threadIdx.x >> 6, l = threadIdx.x & 63;
    const int row = blockIdx.x*4 + w;
    float* hr = h + (size_t)row*CD;
    const float* ar = a0 + (size_t)row*CD;
    const float* a1r = (NADD == 2) ? (a1 + (size_t)row*CD) : nullptr;

    float v[8];
    {
        float4 h0 = ((const float4*)hr)[l*2],  h1 = ((const float4*)hr)[l*2+1];
        float4 b0 = ((const float4*)ar)[l*2],  b1 = ((const float4*)ar)[l*2+1];
        v[0]=h0.x+b0.x; v[1]=h0.y+b0.y; v[2]=h0.z+b0.z; v[3]=h0.w+b0.w;
        v[4]=h1.x+b1.x; v[5]=h1.y+b1.y; v[6]=h1.z+b1.z; v[7]=h1.w+b1.w;
        if (NADD == 2) {
            float4 c0 = ((const float4*)a1r)[l*2], c1 = ((const float4*)a1r)[l*2+1];
            v[0]+=c0.x; v[1]+=c0.y; v[2]+=c0.z; v[3]+=c0.w;
            v[4]+=c1.x; v[5]+=c1.y; v[6]+=c1.z; v[7]+=c1.w;
        }
    }
    float sum = 0.f, sq = 0.f;
#pragma unroll
    for (int i = 0; i < 8; i++) { sum += v[i]; sq += v[i]*v[i]; }
#pragma unroll
    for (int off = 1; off < 64; off <<= 1) {
        sum += __shfl_xor(sum, off);
        sq  += __shfl_xor(sq, off);
    }
    float mean = sum * (1.0f/CD);
    float var  = sq * (1.0f/CD) - mean*mean;
    float rstd = rsqrtf(var + 1e-5f);

    float4 s0 = ((const float4*)s)[l*2],  s1 = ((const float4*)s)[l*2+1];
    float4 g0 = ((const float4*)bv)[l*2], g1 = ((const float4*)bv)[l*2+1];
    float o[8];
    o[0]=(v[0]-mean)*rstd*s0.x+g0.x; o[1]=(v[1]-mean)*rstd*s0.y+g0.y;
    o[2]=(v[2]-mean)*rstd*s0.z+g0.z; o[3]=(v[3]-mean)*rstd*s0.w+g0.w;
    o[4]=(v[4]-mean)*rstd*s1.x+g1.x; o[5]=(v[5]-mean)*rstd*s1.y+g1.y;
    o[6]=(v[6]-mean)*rstd*s1.z+g1.z; o[7]=(v[7]-mean)*rstd*s1.w+g1.w;

    ((float4*)hr)[l*2]   = make_float4(o[0],o[1],o[2],o[3]);
    ((float4*)hr)[l*2+1] = make_float4(o[4],o[5],o[6],o[7]);
    short8 ob;
#pragma unroll
    for (int i = 0; i < 8; i++) ob[i] = (short)f2bfbits(o[i]);
    *(short8*)(hb + (size_t)row*CD + l*8) = ob;
}

// per-layer weight conversion (fallback path)
__global__ __launch_bounds__(256) void k_wconv(const float* __restrict__ a0, const float* __restrict__ a1,
                        const float* __restrict__ a2, const float* __restrict__ a3,
                        bf16* __restrict__ dst) {
    size_t i = ((size_t)blockIdx.x * 256 + threadIdx.x) * 8;
    const float* src; size_t off;
    if (i < 786432)       { src = a0; off = i; }
    else if (i < 1048576) { src = a1; off = i - 786432; }
    else if (i < 2097152) { src = a2; off = i - 1048576; }
    else                  { src = a3; off = i - 2097152; }
    short8 o;
#pragma unroll
    for (int j = 0; j < 8; j++) o[j] = __builtin_bit_cast(short, __float2bfloat16(src[off + j]));
    *(short8*)(void*)(dst + i) = o;
}

// one-shot conversion of all 6 layers' weights
__global__ __launch_bounds__(256) void k_wconv_all(const float* __restrict__ aiw, const float* __restrict__ aow,
                        const float* __restrict__ f1w, const float* __restrict__ f2w,
                        bf16* __restrict__ dst) {
    int lyr = blockIdx.y;
    size_t i = ((size_t)blockIdx.x * 256 + threadIdx.x) * 8;
    const float* src; size_t off;
    if (i < 786432)       { src = aiw + (size_t)lyr* 786432; off = i; }
    else if (i < 1048576) { src = aow + (size_t)lyr* 262144; off = i - 786432; }
    else if (i < 2097152) { src = f1w + (size_t)lyr*1048576; off = i - 1048576; }
    else                  { src = f2w + (size_t)lyr*1048576; off = i - 2097152; }
    short8 o;
#pragma unroll
    for (int j = 0; j < 8; j++) o[j] = __builtin_bit_cast(short, __float2bfloat16(src[off + j]));
    *(short8*)(void*)(dst + (size_t)lyr*3145728 + i) = o;
}

__global__ __launch_bounds__(256) void k_pool(const float* __restrict__ h, float* __restrict__ rep) {
    int b = blockIdx.x, d0 = blockIdx.y * 64;
    int t = threadIdx.x, dl = t & 63, sg = t >> 6;
    float acc = 0.0f;
    for (int s = sg*128; s < sg*128 + 128; s++)
        acc += h[((size_t)(b*CS + s))*CD + d0 + dl];
    __shared__ float red[256];
    red[t] = acc; __syncthreads();
    if (t < 64)
        rep[b*CD + d0 + dl] = (red[t] + red[t+64] + red[t+128] + red[t+192]) * (1.0f/CS);
}

__global__ void k_fc(const float* __restrict__ rep, const float* __restrict__ fcw,
                     const float* __restrict__ fcb, float* __restrict__ out) {
    int b = blockIdx.x, cc = blockIdx.y, l = threadIdx.x;
    float acc = 0.0f;
    for (int d = l; d < CD; d += 64) acc += rep[b*CD + d] * fcw[cc*CD + d];
    for (int o = 32; o > 0; o >>= 1) acc += __shfl_xor(acc, o);
    if (l == 0) out[b*CNC + cc] = acc + fcb[cc];
}

// ---------------------------------------------------------------------------
extern "C" void kernel_launch(void* const* d_in, const int* in_sizes, int n_in,
                              void* d_out, int out_size, void* d_ws, size_t ws_size,
                              hipStream_t stream) {
    const float* x   = (const float*)d_in[0];
    const float* rw1 = (const float*)d_in[1];
    const float* rb1 = (const float*)d_in[2];
    const float* rw2 = (const float*)d_in[3];
    const float* rb2 = (const float*)d_in[4];
    const float* emw = (const float*)d_in[5];
    const float* emb = (const float*)d_in[6];
    const float* aiw = (const float*)d_in[7];
    const float* aib = (const float*)d_in[8];
    const float* aow = (const float*)d_in[9];
    const float* aob = (const float*)d_in[10];
    const float* f1w = (const float*)d_in[11];
    const float* f1b = (const float*)d_in[12];
    const float* f2w = (const float*)d_in[13];
    const float* f2b = (const float*)d_in[14];
    const float* l1s = (const float*)d_in[15];
    const float* l1b = (const float*)d_in[16];
    const float* l2s = (const float*)d_in[17];
    const float* l2b = (const float*)d_in[18];
    const float* fcw = (const float*)d_in[19];
    const float* fcb = (const float*)d_in[20];
    float* out = (float*)d_out;

    char* p = (char*)d_ws;
    auto alloc = [&](size_t bytes) { char* r = p; p += (bytes + 255) & ~(size_t)255; return r; };
    bf16*  biasb = (bf16*)alloc((size_t)CB*CH*CS*CS*2);    // 16.78 MB
    float* h     = (float*)alloc((size_t)CB*CS*CD*4);      // 4.19 MB
    bf16*  hb    = (bf16*)alloc((size_t)CB*CS*CD*2);       // 2.10 MB
    bf16*  qkvb  = (bf16*)alloc((size_t)CB*CS*3*CD*2);     // 6.29 MB
    bf16*  vtb   = (bf16*)alloc((size_t)CB*CH*CDH*CS*2);   // 2.10 MB
    bf16*  attb  = (bf16*)alloc((size_t)CB*CS*CD*2);       // 2.10 MB
    float* tmp   = (float*)alloc((size_t)2*CB*CS*CD*4);    // 8.39 MB (2 split-K slabs)
    bf16*  ffb   = (bf16*)alloc((size_t)CB*CS*CDFF*2);     // 8.39 MB
    bf16*  wl    = (bf16*)alloc((size_t)3145728*2);        // 6.29 MB (per-layer fallback)
    float* rep   = (float*)alloc((size_t)CB*CD*4);
    float* ts    = (float*)alloc(CB*CS*4);
    float* fs    = (float*)alloc(CB*CS*4);

    // one-shot weight buffer if workspace permits (deterministic given fixed ws_size)
    size_t used = (size_t)(p - (char*)d_ws);
    const size_t WLE = 3145728;   // elements per layer (aiw|aow|f1w|f2w)
    bool oneshot = (ws_size > used) && ((ws_size - used) >= (size_t)CL*WLE*2 + 256);
    bf16* wlall = (bf16*)alloc(oneshot ? (size_t)CL*WLE*2 : 0);

    const int M = CB*CS;  // 2048
    float* tmp2 = tmp + (size_t)M*CD;

    k_standardize<<<dim3(CB,2), 256, 0, stream>>>(x, ts, fs);
    k_relpos<<<(CB*CS*CS)/256, 256, 0, stream>>>(ts, fs, rw1, rb1, rw2, rb2, biasb);
    k_embed<<<(M*CD)/256, 256, 0, stream>>>(x, emw, emb, h, hb);
    if (oneshot)
        k_wconv_all<<<dim3(1536, CL), 256, 0, stream>>>(aiw, aow, f1w, f2w, wlall);

    for (int l = 0; l < CL; l++) {
        const bf16* wbase = oneshot ? (wlall + (size_t)l*WLE) : wl;
        if (!oneshot)
            k_wconv<<<1536, 256, 0, stream>>>(aiw + (size_t)l*786432, aow + (size_t)l*262144,
                                              f1w + (size_t)l*1048576, f2w + (size_t)l*1048576, wl);
        const bf16* wl_aiw = wbase;
        const bf16* wl_aow = wbase + 786432;
        const bf16* wl_f1w = wbase + 1048576;
        const bf16* wl_f2w = wbase + 2097152;
        // qkv = h @ aiw^T + aib ; V part written transposed into vtb
        k_mm_qkv<<<dim3(12,16), 512, 0, stream>>>(hb, wl_aiw, aib + (size_t)l*3*CD, qkvb, vtb);
        // fused attention
        k_attn_fused<<<dim3(CS/64, CB*CH), 256, 0, stream>>>(qkvb, vtb, biasb, attb);
        // out projection -> tmp (f32)
        k_mm<64,64,2,1,512><<<dim3(8,32), 512, 0, stream>>>(attb, CD, wl_aow, CD,
                                                            aob + (size_t)l*CD, nullptr, tmp, CD, CD);
        k_ln<1><<<M/4, 256, 0, stream>>>(h, tmp, nullptr, l1s + (size_t)l*CD, l1b + (size_t)l*CD, hb);
        // ff1 (relu)
        k_mm<128,128,1,1,512><<<dim3(16,16), 512, 0, stream>>>(hb, CD, wl_f1w, CD,
                                                               f1b + (size_t)l*CDFF, ffb, nullptr, CDFF, CD);
        // ff2 -> split-K=2 slabs tmp/tmp2 (f32)
        k_mm<64,64,2,2,512><<<dim3(8,32,2), 512, 0, stream>>>(ffb, CDFF, wl_f2w, CDFF,
                                                              f2b + (size_t)l*CD, nullptr, tmp, CD, CDFF);
        k_ln<2><<<M/4, 256, 0, stream>>>(h, tmp, tmp2, l2s + (size_t)l*CD, l2b + (size_t)l*CD, hb);
    }

    k_pool<<<dim3(CB, CD/64), 256, 0, stream>>>(h, rep);
    k_fc<<<dim3(CB, CNC), 64, 0, stream>>>(rep, fcw, fcb, out);
}